// Round 1
// 334.269 us; speedup vs baseline: 1.0313x; 1.0313x over previous
//
#include <hip/hip_runtime.h>
#include <hip/hip_bf16.h>

#define NH      12
#define HD      64
#define HID     768
#define B_      2
#define D_      16
#define QL      32
#define SL      512
#define SEQ     545
#define RPB     8225
#define TOT_ROWS 16450
#define PAD_ROWS 16512       // 129*128
#define VT_R    8256         // Vt rows/batch: cls=0, query 1..32, doc d at 40+d*512
#define WSZ     589824       // 768*768
#define SCALE_  0.125f
#define LOG2E   1.4426950408889634f

typedef __attribute__((ext_vector_type(8))) short short8;
typedef __attribute__((ext_vector_type(4))) short short4v;
typedef __attribute__((ext_vector_type(4))) float float4v;
typedef __attribute__((ext_vector_type(2))) unsigned int uint2v;

__device__ __forceinline__ short f2bf(float f) {
    __hip_bfloat16 h = __float2bfloat16(f);
    short s; __builtin_memcpy(&s, &h, 2);
    return s;
}

// v_cvt_pk_bf16_f32: lo16=bf16(a), hi16=bf16(b) — no builtin on gfx950
__device__ __forceinline__ unsigned int cvtpk(float a, float b) {
    unsigned int r;
    asm("v_cvt_pk_bf16_f32 %0, %1, %2" : "=v"(r) : "v"(a), "v"(b));
    return r;
}

// async global->LDS 16B/lane; lds base wave-uniform (HW adds lane*16)
__device__ __forceinline__ void gl2lds16(const short* g, short* l) {
    __builtin_amdgcn_global_load_lds(
        (const __attribute__((address_space(1))) void*)g,
        (__attribute__((address_space(3))) void*)l, 16, 0, 0);
}

// ---------------------------------------------------------------------------
// Kernel 1: gather cls/query/doc fp32 -> bf16 X [PAD_ROWS x 768]
// ---------------------------------------------------------------------------
__global__ __launch_bounds__(256) void pack_kernel(
    const float* __restrict__ cls, const float* __restrict__ query,
    const float* __restrict__ doc, short* __restrict__ X)
{
    int idx = (blockIdx.x * 256 + threadIdx.x) * 4;
    int row = idx / HID;
    int col = idx - row * HID;
    float4 v = make_float4(0.f, 0.f, 0.f, 0.f);
    if (row < TOT_ROWS) {
        int b = row / RPB;
        int r = row - b * RPB;
        const float* src;
        if (r == 0)        src = cls   + b * HID + col;
        else if (r < 33)   src = query + ((size_t)(b * QL + (r - 1))) * HID + col;
        else               src = doc   + ((size_t)(b * (D_ * SL) + (r - 33))) * HID + col;
        v = *reinterpret_cast<const float4*>(src);
    }
    short4v o;
    o[0] = f2bf(v.x); o[1] = f2bf(v.y); o[2] = f2bf(v.z); o[3] = f2bf(v.w);
    *reinterpret_cast<short4v*>(X + idx) = o;
}

// ---------------------------------------------------------------------------
// Kernel 1b: W fp32 -> bf16 (Wb parked in d_out; attn overwrites all of out)
// ---------------------------------------------------------------------------
__global__ __launch_bounds__(256) void wpack_kernel(
    const float* __restrict__ Wq, const float* __restrict__ Wk,
    const float* __restrict__ Wv, short* __restrict__ Wb)
{
    int idx = (blockIdx.x * 256 + threadIdx.x) * 4;
    int z = idx / WSZ;
    int r = idx - z * WSZ;
    const float* src = (z == 0 ? Wq : (z == 1 ? Wk : Wv)) + r;
    float4 v = *reinterpret_cast<const float4*>(src);
    short4v o;
    o[0] = f2bf(v.x); o[1] = f2bf(v.y); o[2] = f2bf(v.z); o[3] = f2bf(v.w);
    *reinterpret_cast<short4v*>(Wb + idx) = o;
}

// ---------------------------------------------------------------------------
// Kernel 2: projection GEMM, m97 tile (128x128, BK=32), single-barrier
// double-buffered K-loop. Q/K/V merged into ONE dispatch (z=3): removes a
// dispatch boundary + two partial tail-waves of blocks.
// zi==2 (V): A=W-frag, B=X-frag so D[m=wcol][n=xrow]; Vt stores become
// 16-lane contiguous 32B runs along Vt's fast (token) dim.
// ---------------------------------------------------------------------------
__global__ __launch_bounds__(256) void proj4u(
    const short* __restrict__ X, const short* __restrict__ Wb,
    const float* __restrict__ bq, const float* __restrict__ bk,
    const float* __restrict__ bv,
    short* __restrict__ Qb, short* __restrict__ Kb, short* __restrict__ Vt)
{
    __shared__ short Xs[2][128 * 32];
    __shared__ short Ws[2][128 * 32];

    int tid = threadIdx.x, lane = tid & 63, wave = tid >> 6;
    int zi = blockIdx.z;
    bool vsw = (zi == 2);
    const short* W = Wb + (size_t)zi * WSZ;
    int m0 = blockIdx.x * 128, n0 = blockIdx.y * 128;
    int moff = (wave & 1) * 64, noff = (wave >> 1) * 64;
    int lr = lane & 15, lg = lane >> 4, lk = lg * 8;
    int srow = lane >> 2, sk = (lane & 3) * 8;

    const short* xg0 = X + (size_t)(m0 + wave * 32 + srow) * HID + sk;
    const short* xg1 = xg0 + (size_t)16 * HID;
    const short* wg0 = W + (size_t)(n0 + wave * 32 + srow) * HID + sk;
    const short* wg1 = wg0 + (size_t)16 * HID;

    float4v acc[4][4];
    for (int mi = 0; mi < 4; ++mi)
        for (int ni = 0; ni < 4; ++ni)
            acc[mi][ni] = (float4v){0.f, 0.f, 0.f, 0.f};

#define PSTAGE(bufi, kt) do {                                   \
    gl2lds16(xg0 + (kt) * 32, &Xs[bufi][wave * 1024]);          \
    gl2lds16(xg1 + (kt) * 32, &Xs[bufi][wave * 1024 + 512]);    \
    gl2lds16(wg0 + (kt) * 32, &Ws[bufi][wave * 1024]);          \
    gl2lds16(wg1 + (kt) * 32, &Ws[bufi][wave * 1024 + 512]); } while (0)

    PSTAGE(0, 0);
#pragma unroll
    for (int kt = 0; kt < 24; ++kt) {
        __syncthreads();                     // drains stage(kt); prev compute done
        if (kt < 23) PSTAGE((kt + 1) & 1, kt + 1);
        const short* xb = Xs[kt & 1];
        const short* wb = Ws[kt & 1];
        short8 af[4], bf2[4];
        for (int mi = 0; mi < 4; ++mi)
            af[mi]  = *reinterpret_cast<const short8*>(&xb[(moff + mi * 16 + lr) * 32 + lk]);
        for (int ni = 0; ni < 4; ++ni)
            bf2[ni] = *reinterpret_cast<const short8*>(&wb[(noff + ni * 16 + lr) * 32 + lk]);
        if (!vsw) {
            for (int mi = 0; mi < 4; ++mi)
                for (int ni = 0; ni < 4; ++ni)
                    acc[mi][ni] = __builtin_amdgcn_mfma_f32_16x16x32_bf16(
                        af[mi], bf2[ni], acc[mi][ni], 0, 0, 0);
        } else {
            for (int mi = 0; mi < 4; ++mi)
                for (int ni = 0; ni < 4; ++ni)
                    acc[mi][ni] = __builtin_amdgcn_mfma_f32_16x16x32_bf16(
                        bf2[ni], af[mi], acc[mi][ni], 0, 0, 0);
        }
    }
#undef PSTAGE

    if (!vsw) {
        short* Y = zi == 0 ? Qb : Kb;
        const float* bias = zi == 0 ? bq : bk;
        for (int ni = 0; ni < 4; ++ni) {
            int gcol = n0 + noff + ni * 16 + lr;
            float bb = bias[gcol];
            for (int mi = 0; mi < 4; ++mi) {
                int growb = m0 + moff + mi * 16 + lg * 4;
                for (int r = 0; r < 4; ++r)
                    Y[(size_t)(growb + r) * HID + gcol] = f2bf(acc[mi][ni][r] + bb);
            }
        }
    } else {
        // D[m=wcol = noff+ni*16+lg*4+r][n=xrow = moff+mi*16+lr]
        for (int ni = 0; ni < 4; ++ni) {
            float4 b4 = *reinterpret_cast<const float4*>(&bv[n0 + noff + ni * 16 + lg * 4]);
            const float* bbr = reinterpret_cast<const float*>(&b4);
            for (int mi = 0; mi < 4; ++mi) {
                int grow = m0 + moff + mi * 16 + lr;
                if (grow >= TOT_ROWS) continue;
                int b  = grow >= RPB ? 1 : 0;
                int rb = grow - b * RPB;
                int vr = rb < 33 ? rb : rb + 7;        // doc rows at 40+
                size_t cb = ((size_t)(b * HID + n0 + noff + ni * 16 + lg * 4)) * VT_R;
                for (int r = 0; r < 4; ++r)
                    Vt[cb + (size_t)r * VT_R + vr] = f2bf(acc[mi][ni][r] + bbr[r]);
            }
        }
    }
}

// ---------------------------------------------------------------------------
// Kernel 3: flash attention (S^T form, 128 q/block), double-buffered K/V.
// VALU diet vs prior version:
//  - P -> A-fragment repack fully in-register: 8x v_cvt_pk_bf16_f32 +
//    4x permlane32_swap + 4x permlane16_swap replaces 16x f2bf (~50 ops) +
//    Ps LDS write/readback (+ its lgkmcnt stall + bank conflicts).
//  - defer-max (THR=8 in log2 domain): skip alpha rescale (exp2 + 4
//    ds_bpermute + 16 mul) unless the tile max actually grows past m_i+8.
//  - max3-friendly reduction tree for the 16-value row max.
//  - s_setprio(1) around MFMA clusters.
//  - Ps dropped: LDS 44.5KB -> 35.1KB => 4 blocks/CU instead of 2-3.
// Token order: doc 0..511, cls 512, query 513..544, pad 545.. (-inf mask).
// ---------------------------------------------------------------------------
__device__ __forceinline__ int row_of(int b, int d, int t) {
    t = t > 544 ? 544 : t;
    int base = b * RPB;
    if (t < 512)  return base + 33 + d * SL + t;
    if (t == 512) return base;
    return base + (t - 512);
}

__global__ __launch_bounds__(256) void attn4(
    const short* __restrict__ Qb, const short* __restrict__ Kb,
    const short* __restrict__ Vt,
    const float* __restrict__ qmask, const float* __restrict__ dmask,
    float* __restrict__ out)
{
    __shared__ short Ks[2][64 * 64];
    __shared__ short Vs[2][64 * 64];
    __shared__ float maskv[576];

    int tid  = threadIdx.x;
    int lane = tid & 63, wave = tid >> 6;
    int hbd = blockIdx.x;
    int h = hbd >> 5, bd = hbd & 31;
    int b = bd >> 4, d = bd & 15;
    int qc = blockIdx.y;
    int lr = lane & 15, lg = lane >> 4, lk = lg * 8;
    int base = b * RPB;
    const short* vbase = Vt + (size_t)(b * HID + h * HD) * VT_R;

#define ASTAGE(bufi, kt) do {                                               \
    for (int p = 0; p < 2; ++p) {                                           \
        int s2 = p * 256 + tid;                                             \
        int r = s2 >> 3, c = s2 & 7;                                        \
        const short* g = Kb + (size_t)row_of(b, d, (kt) * 64 + r) * HID     \
                       + h * HD + ((c ^ (r & 7)) * 8);                      \
        gl2lds16(g, &Ks[bufi][(p * 256 + (tid & 0xC0)) * 8]);               \
    }                                                                       \
    for (int p = 0; p < 2; ++p) {                                           \
        int s2 = p * 256 + tid;                                             \
        int rd = s2 >> 3, c = s2 & 7;                                       \
        int tc = (kt) * 64 + ((c ^ (rd & 7)) * 8);                          \
        int vr = tc < 512 ? 40 + d * SL + tc : tc - 512;                    \
        gl2lds16(vbase + (size_t)rd * VT_R + vr,                            \
                 &Vs[bufi][(p * 256 + (tid & 0xC0)) * 8]);                  \
    } } while (0)

    ASTAGE(0, 0);

    for (int i = tid; i < 576; i += 256) {
        float mv;
        if (i < 512)       mv = dmask[(size_t)(b * D_ + d) * SL + i];
        else if (i == 512) mv = 0.f;
        else if (i < 545)  mv = qmask[b * QL + (i - 513)];
        else               mv = -INFINITY;
        maskv[i] = mv * LOG2E;
    }

    short8 bq0[2], bq1[2];
    for (int s = 0; s < 2; ++s) {
        int qtok = qc * 128 + s * 64 + wave * 16 + lr;
        int qrow = qtok < 512 ? base + 33 + d * SL + qtok : base + qtok - 512;
        const short* qp = Qb + (size_t)qrow * HID + h * HD + lk;
        bq0[s] = *reinterpret_cast<const short8*>(qp);
        bq1[s] = *reinterpret_cast<const short8*>(qp + 32);
    }

    float m_i[2] = {-1e30f, -1e30f}, l_i[2] = {0.f, 0.f};
    float4v o[2][4];
    for (int s = 0; s < 2; ++s)
        for (int nt = 0; nt < 4; ++nt) o[s][nt] = (float4v){0.f, 0.f, 0.f, 0.f};

    const float qs = SCALE_ * LOG2E;

#pragma unroll
    for (int kt = 0; kt < 9; ++kt) {
        __syncthreads();                    // stage(kt) drained; prev compute done
        if (kt < 8) ASTAGE((kt + 1) & 1, kt + 1);
        const short* kb = Ks[kt & 1];
        const short* vbuf = Vs[kt & 1];

        short8 kf0[4], kf1[4];
        for (int nt = 0; nt < 4; ++nt) {
            int r = nt * 16 + lr;
            int x0 = lg ^ (r & 7);
            kf0[nt] = *reinterpret_cast<const short8*>(&kb[r * 64 + x0 * 8]);
            kf1[nt] = *reinterpret_cast<const short8*>(&kb[r * 64 + (x0 ^ 4) * 8]);
        }

        for (int s = 0; s < 2; ++s) {
            // ---- QK^T: lane holds P[key = kt*64+nt*16+lg*4+r][q = lr] ----
            float p4[4][4];
            __builtin_amdgcn_s_setprio(1);
            for (int nt = 0; nt < 4; ++nt) {
                float4v z = (float4v){0.f, 0.f, 0.f, 0.f};
                z = __builtin_amdgcn_mfma_f32_16x16x32_bf16(kf0[nt], bq0[s], z, 0, 0, 0);
                z = __builtin_amdgcn_mfma_f32_16x16x32_bf16(kf1[nt], bq1[s], z, 0, 0, 0);
                float4v mk = *reinterpret_cast<const float4v*>(
                    &maskv[kt * 64 + nt * 16 + lg * 4]);
                for (int r = 0; r < 4; ++r) p4[nt][r] = z[r] * qs + mk[r];
            }
            __builtin_amdgcn_s_setprio(0);

            // ---- row max (per q = lr) — max3-fusable tree ----
            float a0 = fmaxf(fmaxf(p4[0][0], p4[0][1]), p4[0][2]);
            float a1 = fmaxf(fmaxf(p4[0][3], p4[1][0]), p4[1][1]);
            float a2 = fmaxf(fmaxf(p4[1][2], p4[1][3]), p4[2][0]);
            float a3 = fmaxf(fmaxf(p4[2][1], p4[2][2]), p4[2][3]);
            float a4 = fmaxf(fmaxf(p4[3][0], p4[3][1]), p4[3][2]);
            float b0 = fmaxf(fmaxf(a0, a1), a2);
            float b1 = fmaxf(fmaxf(a3, a4), p4[3][3]);
            float tmx = fmaxf(b0, b1);
            tmx = fmaxf(tmx, __shfl_xor(tmx, 16));
            tmx = fmaxf(tmx, __shfl_xor(tmx, 32));

            // ---- defer-max: rescale only if the tile max grows past m+8 ----
            if (__any(tmx > m_i[s] + 8.0f)) {
                float mnew = fmaxf(m_i[s], tmx);
                float alpha = exp2f(m_i[s] - mnew);
                m_i[s] = mnew;
                l_i[s] *= alpha;
                float al[4];
                for (int r = 0; r < 4; ++r) al[r] = __shfl(alpha, lg * 4 + r);
                for (int nt = 0; nt < 4; ++nt)
                    for (int r = 0; r < 4; ++r) o[s][nt][r] *= al[r];
            }

            // ---- exp2 + row sum (P bounded by 2^8) ----
            float sum = 0.f;
            for (int nt = 0; nt < 4; ++nt)
                for (int r = 0; r < 4; ++r) {
                    p4[nt][r] = exp2f(p4[nt][r] - m_i[s]);
                    sum += p4[nt][r];
                }
            sum += __shfl_xor(sum, 16);
            sum += __shfl_xor(sum, 32);
            l_i[s] += sum;

            // ---- in-register P -> PV A-fragment repack ----
            // w{A,B}[nt] @ group g' hold keys nt*16+g'*4+{0,1}/{2,3} (q=lr).
            // permlane16(permlane32(w[n], w[n+1])) = ([w_n@g0, w_n@g2,
            // w_{n+1}@g0, w_{n+1}@g2], [w_n@g1, w_n@g3, w_{n+1}@g1, w_{n+1}@g3])
            // = (dw0, dw2) of the A-fragment (keys 8*lg+2d, +2d+1 per dword d).
            unsigned int wa[4], wbv[4];
            for (int nt = 0; nt < 4; ++nt) {
                wa[nt]  = cvtpk(p4[nt][0], p4[nt][1]);
                wbv[nt] = cvtpk(p4[nt][2], p4[nt][3]);
            }
            uint2v tA01 = __builtin_amdgcn_permlane32_swap(wa[0],  wa[1],  false, false);
            uint2v uA01 = __builtin_amdgcn_permlane16_swap(tA01[0], tA01[1], false, false);
            uint2v tB01 = __builtin_amdgcn_permlane32_swap(wbv[0], wbv[1], false, false);
            uint2v uB01 = __builtin_amdgcn_permlane16_swap(tB01[0], tB01[1], false, false);
            uint2v tA23 = __builtin_amdgcn_permlane32_swap(wa[2],  wa[3],  false, false);
            uint2v uA23 = __builtin_amdgcn_permlane16_swap(tA23[0], tA23[1], false, false);
            uint2v tB23 = __builtin_amdgcn_permlane32_swap(wbv[2], wbv[3], false, false);
            uint2v uB23 = __builtin_amdgcn_permlane16_swap(tB23[0], tB23[1], false, false);

            union { unsigned int u[4]; short8 s8; } A0, A1;
            A0.u[0] = uA01[0]; A0.u[1] = uB01[0]; A0.u[2] = uA01[1]; A0.u[3] = uB01[1];
            A1.u[0] = uA23[0]; A1.u[1] = uB23[0]; A1.u[2] = uA23[1]; A1.u[3] = uB23[1];
            short8 ap0 = A0.s8;
            short8 ap1 = A1.s8;

            // ---- PV ----
            __builtin_amdgcn_s_setprio(1);
            for (int nt = 0; nt < 4; ++nt) {
                int rd = nt * 16 + lr;
                int x0 = lg ^ (rd & 7);
                short8 bv0 = *reinterpret_cast<const short8*>(&vbuf[rd * 64 + x0 * 8]);
                short8 bv1 = *reinterpret_cast<const short8*>(&vbuf[rd * 64 + (x0 ^ 4) * 8]);
                o[s][nt] = __builtin_amdgcn_mfma_f32_16x16x32_bf16(ap0, bv0, o[s][nt], 0, 0, 0);
                o[s][nt] = __builtin_amdgcn_mfma_f32_16x16x32_bf16(ap1, bv1, o[s][nt], 0, 0, 0);
            }
            __builtin_amdgcn_s_setprio(0);
        }
    }
#undef ASTAGE

    for (int s = 0; s < 2; ++s) {
        float li[4];
        for (int r = 0; r < 4; ++r) li[r] = __shfl(l_i[s], lg * 4 + r);
        for (int r = 0; r < 4; ++r) {
            int t = qc * 128 + s * 64 + wave * 16 + lg * 4 + r;
            if (t >= SEQ) continue;
            int seq = t < 512 ? 33 + t : (t == 512 ? 0 : t - 512);
            float inv = 1.f / li[r];
            float* op = out + ((size_t)(bd * SEQ + seq)) * HID + h * HD + lr;
            for (int nt = 0; nt < 4; ++nt)
                op[nt * 16] = o[s][nt][r] * inv;
        }
    }
}

// ---------------------------------------------------------------------------
extern "C" void kernel_launch(void* const* d_in, const int* in_sizes, int n_in,
                              void* d_out, int out_size, void* d_ws, size_t ws_size,
                              hipStream_t stream)
{
    const float* cls   = (const float*)d_in[0];
    const float* query = (const float*)d_in[1];
    const float* doc   = (const float*)d_in[2];
    const float* qmask = (const float*)d_in[3];
    const float* dmask = (const float*)d_in[4];
    const float* Wq = (const float*)d_in[5];
    const float* bq = (const float*)d_in[6];
    const float* Wk = (const float*)d_in[7];
    const float* bk = (const float*)d_in[8];
    const float* Wv = (const float*)d_in[9];
    const float* bv = (const float*)d_in[10];
    float* out = (float*)d_out;

    short* X  = (short*)d_ws;
    size_t seg = (size_t)PAD_ROWS * HID;
    short* Qb = X + seg;
    short* Kb = Qb + seg;
    short* Vt = Kb + seg;                 // 2*768*8256 == seg
    short* Wb = (short*)d_out;            // scratch; attn4 overwrites all of out

    pack_kernel<<<dim3((PAD_ROWS * HID / 4) / 256), 256, 0, stream>>>(cls, query, doc, X);
    wpack_kernel<<<dim3((3 * WSZ / 4) / 256), 256, 0, stream>>>(Wq, Wk, Wv, Wb);
    proj4u<<<dim3(129, 6, 3), 256, 0, stream>>>(X, Wb, bq, bk, bv, Qb, Kb, Vt);
    attn4<<<dim3(NH * 32, 5), 256, 0, stream>>>(Qb, Kb, Vt, qmask, dmask, out);
}

// Round 2
// 312.825 us; speedup vs baseline: 1.1020x; 1.0685x over previous
//
#include <hip/hip_runtime.h>
#include <hip/hip_bf16.h>

#define NH      12
#define HD      64
#define HID     768
#define B_      2
#define D_      16
#define QL      32
#define SL      512
#define SEQ     545
#define RPB     8225
#define TOT_ROWS 16450
#define PAD_ROWS 16512       // 129*128
#define VT_R    8256         // Vt rows/batch: cls=0, query 1..32, doc d at 40+d*512
#define WSZ     589824       // 768*768
#define SCALE_  0.125f
#define LOG2E   1.4426950408889634f

typedef __attribute__((ext_vector_type(8))) short short8;
typedef __attribute__((ext_vector_type(4))) short short4v;
typedef __attribute__((ext_vector_type(4))) float float4v;
typedef __attribute__((ext_vector_type(2))) unsigned int uint2v;

__device__ __forceinline__ short f2bf(float f) {
    __hip_bfloat16 h = __float2bfloat16(f);
    short s; __builtin_memcpy(&s, &h, 2);
    return s;
}

// v_cvt_pk_bf16_f32: lo16=bf16(a), hi16=bf16(b) — no builtin on gfx950
__device__ __forceinline__ unsigned int cvtpk(float a, float b) {
    unsigned int r;
    asm("v_cvt_pk_bf16_f32 %0, %1, %2" : "=v"(r) : "v"(a), "v"(b));
    return r;
}

// async global->LDS 16B/lane; lds base wave-uniform (HW adds lane*16)
__device__ __forceinline__ void gl2lds16(const short* g, short* l) {
    __builtin_amdgcn_global_load_lds(
        (const __attribute__((address_space(1))) void*)g,
        (__attribute__((address_space(3))) void*)l, 16, 0, 0);
}

// ---------------------------------------------------------------------------
// Kernel 1: gather cls/query/doc fp32 -> bf16 X [PAD_ROWS x 768]
// ---------------------------------------------------------------------------
__global__ __launch_bounds__(256) void pack_kernel(
    const float* __restrict__ cls, const float* __restrict__ query,
    const float* __restrict__ doc, short* __restrict__ X)
{
    int idx = (blockIdx.x * 256 + threadIdx.x) * 4;
    int row = idx / HID;
    int col = idx - row * HID;
    float4 v = make_float4(0.f, 0.f, 0.f, 0.f);
    if (row < TOT_ROWS) {
        int b = row / RPB;
        int r = row - b * RPB;
        const float* src;
        if (r == 0)        src = cls   + b * HID + col;
        else if (r < 33)   src = query + ((size_t)(b * QL + (r - 1))) * HID + col;
        else               src = doc   + ((size_t)(b * (D_ * SL) + (r - 33))) * HID + col;
        v = *reinterpret_cast<const float4*>(src);
    }
    short4v o;
    o[0] = f2bf(v.x); o[1] = f2bf(v.y); o[2] = f2bf(v.z); o[3] = f2bf(v.w);
    *reinterpret_cast<short4v*>(X + idx) = o;
}

// ---------------------------------------------------------------------------
// Kernel 1b: W fp32 -> bf16 (Wb parked in d_out; attn overwrites all of out)
// ---------------------------------------------------------------------------
__global__ __launch_bounds__(256) void wpack_kernel(
    const float* __restrict__ Wq, const float* __restrict__ Wk,
    const float* __restrict__ Wv, short* __restrict__ Wb)
{
    int idx = (blockIdx.x * 256 + threadIdx.x) * 4;
    int z = idx / WSZ;
    int r = idx - z * WSZ;
    const float* src = (z == 0 ? Wq : (z == 1 ? Wk : Wv)) + r;
    float4 v = *reinterpret_cast<const float4*>(src);
    short4v o;
    o[0] = f2bf(v.x); o[1] = f2bf(v.y); o[2] = f2bf(v.z); o[3] = f2bf(v.w);
    *reinterpret_cast<short4v*>(Wb + idx) = o;
}

// ---------------------------------------------------------------------------
// Kernel 2: projection GEMM, m97 tile (128x128, BK=32), single-barrier
// double-buffered K-loop. Q/K/V in ONE dispatch.
// Grid locality fix: grid=(18,129); fast dim = (n,z) so 18 consecutive
// blocks share one 196KB X-tile and collectively read all of W (3.5MB ->
// stays hot in L2). XCD-chunked bijective remap (m204): each XCD owns a
// contiguous m-range, so its X slice (~3.2MB) lives in its private L2.
// zi==2 (V): A=W-frag, B=X-frag so D[m=wcol][n=xrow]; Vt stores become
// 16-lane contiguous 32B runs along Vt's fast (token) dim.
// ---------------------------------------------------------------------------
__global__ __launch_bounds__(256) void proj4u(
    const short* __restrict__ X, const short* __restrict__ Wb,
    const float* __restrict__ bq, const float* __restrict__ bk,
    const float* __restrict__ bv,
    short* __restrict__ Qb, short* __restrict__ Kb, short* __restrict__ Vt)
{
    __shared__ short Xs[2][128 * 32];
    __shared__ short Ws[2][128 * 32];

    int tid = threadIdx.x, lane = tid & 63, wave = tid >> 6;

    // ---- XCD-aware bijective remap: nwg = 18*129 = 2322 = 8*290 + 2 ----
    int lin = blockIdx.x + 18 * blockIdx.y;
    {
        const int q = 290, r = 2;
        int xcd = lin & 7, seq = lin >> 3;
        lin = (xcd < r ? xcd * (q + 1) : r * (q + 1) + (xcd - r) * q) + seq;
    }
    int mblk = lin / 18;
    int nz   = lin - mblk * 18;
    int zi   = nz % 3;          // z fastest
    int nblk = nz / 3;
    bool vsw = (zi == 2);
    const short* W = Wb + (size_t)zi * WSZ;
    int m0 = mblk * 128, n0 = nblk * 128;

    int moff = (wave & 1) * 64, noff = (wave >> 1) * 64;
    int lr = lane & 15, lg = lane >> 4, lk = lg * 8;
    int srow = lane >> 2, sk = (lane & 3) * 8;

    const short* xg0 = X + (size_t)(m0 + wave * 32 + srow) * HID + sk;
    const short* xg1 = xg0 + (size_t)16 * HID;
    const short* wg0 = W + (size_t)(n0 + wave * 32 + srow) * HID + sk;
    const short* wg1 = wg0 + (size_t)16 * HID;

    float4v acc[4][4];
    for (int mi = 0; mi < 4; ++mi)
        for (int ni = 0; ni < 4; ++ni)
            acc[mi][ni] = (float4v){0.f, 0.f, 0.f, 0.f};

#define PSTAGE(bufi, kt) do {                                   \
    gl2lds16(xg0 + (kt) * 32, &Xs[bufi][wave * 1024]);          \
    gl2lds16(xg1 + (kt) * 32, &Xs[bufi][wave * 1024 + 512]);    \
    gl2lds16(wg0 + (kt) * 32, &Ws[bufi][wave * 1024]);          \
    gl2lds16(wg1 + (kt) * 32, &Ws[bufi][wave * 1024 + 512]); } while (0)

    PSTAGE(0, 0);
#pragma unroll
    for (int kt = 0; kt < 24; ++kt) {
        __syncthreads();                     // drains stage(kt); prev compute done
        if (kt < 23) PSTAGE((kt + 1) & 1, kt + 1);
        const short* xb = Xs[kt & 1];
        const short* wb = Ws[kt & 1];
        short8 af[4], bf2[4];
        for (int mi = 0; mi < 4; ++mi)
            af[mi]  = *reinterpret_cast<const short8*>(&xb[(moff + mi * 16 + lr) * 32 + lk]);
        for (int ni = 0; ni < 4; ++ni)
            bf2[ni] = *reinterpret_cast<const short8*>(&wb[(noff + ni * 16 + lr) * 32 + lk]);
        if (!vsw) {
            for (int mi = 0; mi < 4; ++mi)
                for (int ni = 0; ni < 4; ++ni)
                    acc[mi][ni] = __builtin_amdgcn_mfma_f32_16x16x32_bf16(
                        af[mi], bf2[ni], acc[mi][ni], 0, 0, 0);
        } else {
            for (int mi = 0; mi < 4; ++mi)
                for (int ni = 0; ni < 4; ++ni)
                    acc[mi][ni] = __builtin_amdgcn_mfma_f32_16x16x32_bf16(
                        bf2[ni], af[mi], acc[mi][ni], 0, 0, 0);
        }
    }
#undef PSTAGE

    if (!vsw) {
        short* Y = zi == 0 ? Qb : Kb;
        const float* bias = zi == 0 ? bq : bk;
        for (int ni = 0; ni < 4; ++ni) {
            int gcol = n0 + noff + ni * 16 + lr;
            float bb = bias[gcol];
            for (int mi = 0; mi < 4; ++mi) {
                int growb = m0 + moff + mi * 16 + lg * 4;
                for (int r = 0; r < 4; ++r)
                    Y[(size_t)(growb + r) * HID + gcol] = f2bf(acc[mi][ni][r] + bb);
            }
        }
    } else {
        // D[m=wcol = noff+ni*16+lg*4+r][n=xrow = moff+mi*16+lr]
        for (int ni = 0; ni < 4; ++ni) {
            float4 b4 = *reinterpret_cast<const float4*>(&bv[n0 + noff + ni * 16 + lg * 4]);
            const float* bbr = reinterpret_cast<const float*>(&b4);
            for (int mi = 0; mi < 4; ++mi) {
                int grow = m0 + moff + mi * 16 + lr;
                if (grow >= TOT_ROWS) continue;
                int b  = grow >= RPB ? 1 : 0;
                int rb = grow - b * RPB;
                int vr = rb < 33 ? rb : rb + 7;        // doc rows at 40+
                size_t cb = ((size_t)(b * HID + n0 + noff + ni * 16 + lg * 4)) * VT_R;
                for (int r = 0; r < 4; ++r)
                    Vt[cb + (size_t)r * VT_R + vr] = f2bf(acc[mi][ni][r] + bbr[r]);
            }
        }
    }
}

// ---------------------------------------------------------------------------
// Kernel 3: flash attention (S^T form, 128 q/block), double-buffered K/V.
// Grid locality fix: grid=(5,384); fast dim = qc so the 5 blocks sharing a
// 140KB K/V (h,b,d) slice are adjacent in dispatch (L2 reuse). XCD-chunked
// remap keeps each XCD on a contiguous hbd range.
// Token order: doc 0..511, cls 512, query 513..544, pad 545.. (-inf mask).
// ---------------------------------------------------------------------------
__device__ __forceinline__ int row_of(int b, int d, int t) {
    t = t > 544 ? 544 : t;
    int base = b * RPB;
    if (t < 512)  return base + 33 + d * SL + t;
    if (t == 512) return base;
    return base + (t - 512);
}

__global__ __launch_bounds__(256) void attn4(
    const short* __restrict__ Qb, const short* __restrict__ Kb,
    const short* __restrict__ Vt,
    const float* __restrict__ qmask, const float* __restrict__ dmask,
    float* __restrict__ out)
{
    __shared__ short Ks[2][64 * 64];
    __shared__ short Vs[2][64 * 64];
    __shared__ float maskv[576];

    int tid  = threadIdx.x;
    int lane = tid & 63, wave = tid >> 6;

    // ---- XCD-aware remap: nwg = 5*384 = 1920 = 8*240 ----
    int lin = blockIdx.x + 5 * blockIdx.y;
    {
        int xcd = lin & 7, seq = lin >> 3;
        lin = xcd * 240 + seq;
    }
    int hbd = lin / 5;
    int qc  = lin - hbd * 5;
    int h = hbd >> 5, bd = hbd & 31;
    int b = bd >> 4, d = bd & 15;

    int lr = lane & 15, lg = lane >> 4, lk = lg * 8;
    int base = b * RPB;
    const short* vbase = Vt + (size_t)(b * HID + h * HD) * VT_R;

#define ASTAGE(bufi, kt) do {                                               \
    for (int p = 0; p < 2; ++p) {                                           \
        int s2 = p * 256 + tid;                                             \
        int r = s2 >> 3, c = s2 & 7;                                        \
        const short* g = Kb + (size_t)row_of(b, d, (kt) * 64 + r) * HID     \
                       + h * HD + ((c ^ (r & 7)) * 8);                      \
        gl2lds16(g, &Ks[bufi][(p * 256 + (tid & 0xC0)) * 8]);               \
    }                                                                       \
    for (int p = 0; p < 2; ++p) {                                           \
        int s2 = p * 256 + tid;                                             \
        int rd = s2 >> 3, c = s2 & 7;                                       \
        int tc = (kt) * 64 + ((c ^ (rd & 7)) * 8);                          \
        int vr = tc < 512 ? 40 + d * SL + tc : tc - 512;                    \
        gl2lds16(vbase + (size_t)rd * VT_R + vr,                            \
                 &Vs[bufi][(p * 256 + (tid & 0xC0)) * 8]);                  \
    } } while (0)

    ASTAGE(0, 0);

    for (int i = tid; i < 576; i += 256) {
        float mv;
        if (i < 512)       mv = dmask[(size_t)(b * D_ + d) * SL + i];
        else if (i == 512) mv = 0.f;
        else if (i < 545)  mv = qmask[b * QL + (i - 513)];
        else               mv = -INFINITY;
        maskv[i] = mv * LOG2E;
    }

    short8 bq0[2], bq1[2];
    for (int s = 0; s < 2; ++s) {
        int qtok = qc * 128 + s * 64 + wave * 16 + lr;
        int qrow = qtok < 512 ? base + 33 + d * SL + qtok : base + qtok - 512;
        const short* qp = Qb + (size_t)qrow * HID + h * HD + lk;
        bq0[s] = *reinterpret_cast<const short8*>(qp);
        bq1[s] = *reinterpret_cast<const short8*>(qp + 32);
    }

    float m_i[2] = {-1e30f, -1e30f}, l_i[2] = {0.f, 0.f};
    float4v o[2][4];
    for (int s = 0; s < 2; ++s)
        for (int nt = 0; nt < 4; ++nt) o[s][nt] = (float4v){0.f, 0.f, 0.f, 0.f};

    const float qs = SCALE_ * LOG2E;

#pragma unroll
    for (int kt = 0; kt < 9; ++kt) {
        __syncthreads();                    // stage(kt) drained; prev compute done
        if (kt < 8) ASTAGE((kt + 1) & 1, kt + 1);
        const short* kb = Ks[kt & 1];
        const short* vbuf = Vs[kt & 1];

        short8 kf0[4], kf1[4];
        for (int nt = 0; nt < 4; ++nt) {
            int r = nt * 16 + lr;
            int x0 = lg ^ (r & 7);
            kf0[nt] = *reinterpret_cast<const short8*>(&kb[r * 64 + x0 * 8]);
            kf1[nt] = *reinterpret_cast<const short8*>(&kb[r * 64 + (x0 ^ 4) * 8]);
        }

        for (int s = 0; s < 2; ++s) {
            // ---- QK^T: lane holds P[key = kt*64+nt*16+lg*4+r][q = lr] ----
            float p4[4][4];
            __builtin_amdgcn_s_setprio(1);
            for (int nt = 0; nt < 4; ++nt) {
                float4v z = (float4v){0.f, 0.f, 0.f, 0.f};
                z = __builtin_amdgcn_mfma_f32_16x16x32_bf16(kf0[nt], bq0[s], z, 0, 0, 0);
                z = __builtin_amdgcn_mfma_f32_16x16x32_bf16(kf1[nt], bq1[s], z, 0, 0, 0);
                float4v mk = *reinterpret_cast<const float4v*>(
                    &maskv[kt * 64 + nt * 16 + lg * 4]);
                for (int r = 0; r < 4; ++r) p4[nt][r] = z[r] * qs + mk[r];
            }
            __builtin_amdgcn_s_setprio(0);

            // ---- row max (per q = lr) — max3-fusable tree ----
            float a0 = fmaxf(fmaxf(p4[0][0], p4[0][1]), p4[0][2]);
            float a1 = fmaxf(fmaxf(p4[0][3], p4[1][0]), p4[1][1]);
            float a2 = fmaxf(fmaxf(p4[1][2], p4[1][3]), p4[2][0]);
            float a3 = fmaxf(fmaxf(p4[2][1], p4[2][2]), p4[2][3]);
            float a4 = fmaxf(fmaxf(p4[3][0], p4[3][1]), p4[3][2]);
            float b0 = fmaxf(fmaxf(a0, a1), a2);
            float b1 = fmaxf(fmaxf(a3, a4), p4[3][3]);
            float tmx = fmaxf(b0, b1);
            tmx = fmaxf(tmx, __shfl_xor(tmx, 16));
            tmx = fmaxf(tmx, __shfl_xor(tmx, 32));

            // ---- defer-max: rescale only if the tile max grows past m+8 ----
            if (__any(tmx > m_i[s] + 8.0f)) {
                float mnew = fmaxf(m_i[s], tmx);
                float alpha = exp2f(m_i[s] - mnew);
                m_i[s] = mnew;
                l_i[s] *= alpha;
                float al[4];
                for (int r = 0; r < 4; ++r) al[r] = __shfl(alpha, lg * 4 + r);
                for (int nt = 0; nt < 4; ++nt)
                    for (int r = 0; r < 4; ++r) o[s][nt][r] *= al[r];
            }

            // ---- exp2 + row sum (P bounded by 2^8) ----
            float sum = 0.f;
            for (int nt = 0; nt < 4; ++nt)
                for (int r = 0; r < 4; ++r) {
                    p4[nt][r] = exp2f(p4[nt][r] - m_i[s]);
                    sum += p4[nt][r];
                }
            sum += __shfl_xor(sum, 16);
            sum += __shfl_xor(sum, 32);
            l_i[s] += sum;

            // ---- in-register P -> PV A-fragment repack ----
            unsigned int wa[4], wbv[4];
            for (int nt = 0; nt < 4; ++nt) {
                wa[nt]  = cvtpk(p4[nt][0], p4[nt][1]);
                wbv[nt] = cvtpk(p4[nt][2], p4[nt][3]);
            }
            uint2v tA01 = __builtin_amdgcn_permlane32_swap(wa[0],  wa[1],  false, false);
            uint2v uA01 = __builtin_amdgcn_permlane16_swap(tA01[0], tA01[1], false, false);
            uint2v tB01 = __builtin_amdgcn_permlane32_swap(wbv[0], wbv[1], false, false);
            uint2v uB01 = __builtin_amdgcn_permlane16_swap(tB01[0], tB01[1], false, false);
            uint2v tA23 = __builtin_amdgcn_permlane32_swap(wa[2],  wa[3],  false, false);
            uint2v uA23 = __builtin_amdgcn_permlane16_swap(tA23[0], tA23[1], false, false);
            uint2v tB23 = __builtin_amdgcn_permlane32_swap(wbv[2], wbv[3], false, false);
            uint2v uB23 = __builtin_amdgcn_permlane16_swap(tB23[0], tB23[1], false, false);

            union { unsigned int u[4]; short8 s8; } A0, A1;
            A0.u[0] = uA01[0]; A0.u[1] = uB01[0]; A0.u[2] = uA01[1]; A0.u[3] = uB01[1];
            A1.u[0] = uA23[0]; A1.u[1] = uB23[0]; A1.u[2] = uA23[1]; A1.u[3] = uB23[1];
            short8 ap0 = A0.s8;
            short8 ap1 = A1.s8;

            // ---- PV ----
            __builtin_amdgcn_s_setprio(1);
            for (int nt = 0; nt < 4; ++nt) {
                int rd = nt * 16 + lr;
                int x0 = lg ^ (rd & 7);
                short8 bv0 = *reinterpret_cast<const short8*>(&vbuf[rd * 64 + x0 * 8]);
                short8 bv1 = *reinterpret_cast<const short8*>(&vbuf[rd * 64 + (x0 ^ 4) * 8]);
                o[s][nt] = __builtin_amdgcn_mfma_f32_16x16x32_bf16(ap0, bv0, o[s][nt], 0, 0, 0);
                o[s][nt] = __builtin_amdgcn_mfma_f32_16x16x32_bf16(ap1, bv1, o[s][nt], 0, 0, 0);
            }
            __builtin_amdgcn_s_setprio(0);
        }
    }
#undef ASTAGE

    for (int s = 0; s < 2; ++s) {
        float li[4];
        for (int r = 0; r < 4; ++r) li[r] = __shfl(l_i[s], lg * 4 + r);
        for (int r = 0; r < 4; ++r) {
            int t = qc * 128 + s * 64 + wave * 16 + lg * 4 + r;
            if (t >= SEQ) continue;
            int seq = t < 512 ? 33 + t : (t == 512 ? 0 : t - 512);
            float inv = 1.f / li[r];
            float* op = out + ((size_t)(bd * SEQ + seq)) * HID + h * HD + lr;
            for (int nt = 0; nt < 4; ++nt)
                op[nt * 16] = o[s][nt][r] * inv;
        }
    }
}

// ---------------------------------------------------------------------------
extern "C" void kernel_launch(void* const* d_in, const int* in_sizes, int n_in,
                              void* d_out, int out_size, void* d_ws, size_t ws_size,
                              hipStream_t stream)
{
    const float* cls   = (const float*)d_in[0];
    const float* query = (const float*)d_in[1];
    const float* doc   = (const float*)d_in[2];
    const float* qmask = (const float*)d_in[3];
    const float* dmask = (const float*)d_in[4];
    const float* Wq = (const float*)d_in[5];
    const float* bq = (const float*)d_in[6];
    const float* Wk = (const float*)d_in[7];
    const float* bk = (const float*)d_in[8];
    const float* Wv = (const float*)d_in[9];
    const float* bv = (const float*)d_in[10];
    float* out = (float*)d_out;

    short* X  = (short*)d_ws;
    size_t seg = (size_t)PAD_ROWS * HID;
    short* Qb = X + seg;
    short* Kb = Qb + seg;
    short* Vt = Kb + seg;                 // 2*768*8256 == seg
    short* Wb = (short*)d_out;            // scratch; attn4 overwrites all of out

    pack_kernel<<<dim3((PAD_ROWS * HID / 4) / 256), 256, 0, stream>>>(cls, query, doc, X);
    wpack_kernel<<<dim3((3 * WSZ / 4) / 256), 256, 0, stream>>>(Wq, Wk, Wv, Wb);
    proj4u<<<dim3(18, 129, 1), 256, 0, stream>>>(X, Wb, bq, bk, bv, Qb, Kb, Vt);
    attn4<<<dim3(5, NH * 32, 1), 256, 0, stream>>>(Qb, Kb, Vt, qmask, dmask, out);
}

// Round 3
// 304.153 us; speedup vs baseline: 1.1334x; 1.0285x over previous
//
#include <hip/hip_runtime.h>
#include <hip/hip_bf16.h>

#define NH      12
#define HD      64
#define HID     768
#define B_      2
#define D_      16
#define QL      32
#define SL      512
#define SEQ     545
#define RPB     8225
#define TOT_ROWS 16450
#define PAD_ROWS 16512       // 129*128
#define VT_R    8256         // Vt rows/batch: cls=0, query 1..32, doc d at 40+d*512
#define WSZ     589824       // 768*768
#define SCALE_  0.125f
#define LOG2E   1.4426950408889634f
#define QSF     0.18033688011112042f   // SCALE_*LOG2E, folded into Wq/bq

typedef __attribute__((ext_vector_type(8))) short short8;
typedef __attribute__((ext_vector_type(4))) short short4v;
typedef __attribute__((ext_vector_type(4))) float float4v;
typedef __attribute__((ext_vector_type(2))) unsigned int uint2v;

__device__ __forceinline__ short f2bf(float f) {
    __hip_bfloat16 h = __float2bfloat16(f);
    short s; __builtin_memcpy(&s, &h, 2);
    return s;
}

// v_cvt_pk_bf16_f32: lo16=bf16(a), hi16=bf16(b) — no builtin on gfx950
__device__ __forceinline__ unsigned int cvtpk(float a, float b) {
    unsigned int r;
    asm("v_cvt_pk_bf16_f32 %0, %1, %2" : "=v"(r) : "v"(a), "v"(b));
    return r;
}

// async global->LDS 16B/lane; lds base wave-uniform (HW adds lane*16)
__device__ __forceinline__ void gl2lds16(const short* g, short* l) {
    __builtin_amdgcn_global_load_lds(
        (const __attribute__((address_space(1))) void*)g,
        (__attribute__((address_space(3))) void*)l, 16, 0, 0);
}

#define PACK_BLKS  12384     // PAD_ROWS*HID/4/256
#define WPACK_BLKS 1728      // 3*WSZ/4/256

// ---------------------------------------------------------------------------
// Kernel 1 (fused): gather cls/query/doc fp32 -> bf16 X [PAD_ROWS x 768],
// and W fp32 -> bf16 (Wq pre-scaled by SCALE*log2e; Wb parked in d_out).
// ---------------------------------------------------------------------------
__global__ __launch_bounds__(256) void pack_all(
    const float* __restrict__ cls, const float* __restrict__ query,
    const float* __restrict__ doc,
    const float* __restrict__ Wq, const float* __restrict__ Wk,
    const float* __restrict__ Wv,
    short* __restrict__ X, short* __restrict__ Wb)
{
    int bid = blockIdx.x;
    if (bid < PACK_BLKS) {
        int idx = (bid * 256 + threadIdx.x) * 4;
        int row = idx / HID;
        int col = idx - row * HID;
        float4 v = make_float4(0.f, 0.f, 0.f, 0.f);
        if (row < TOT_ROWS) {
            int b = row / RPB;
            int r = row - b * RPB;
            const float* src;
            if (r == 0)        src = cls   + b * HID + col;
            else if (r < 33)   src = query + ((size_t)(b * QL + (r - 1))) * HID + col;
            else               src = doc   + ((size_t)(b * (D_ * SL) + (r - 33))) * HID + col;
            v = *reinterpret_cast<const float4*>(src);
        }
        short4v o;
        o[0] = f2bf(v.x); o[1] = f2bf(v.y); o[2] = f2bf(v.z); o[3] = f2bf(v.w);
        *reinterpret_cast<short4v*>(X + idx) = o;
    } else {
        int idx = ((bid - PACK_BLKS) * 256 + threadIdx.x) * 4;
        int z = idx / WSZ;
        int r = idx - z * WSZ;
        const float* src = (z == 0 ? Wq : (z == 1 ? Wk : Wv)) + r;
        float sc = (z == 0) ? QSF : 1.0f;   // fold qk-scale*log2e into Wq
        float4 v = *reinterpret_cast<const float4*>(src);
        short4v o;
        o[0] = f2bf(v.x * sc); o[1] = f2bf(v.y * sc);
        o[2] = f2bf(v.z * sc); o[3] = f2bf(v.w * sc);
        *reinterpret_cast<short4v*>(Wb + idx) = o;
    }
}

// ---------------------------------------------------------------------------
// Kernel 2: projection GEMM, m97 tile (128x128, BK=32), single-barrier
// double-buffered K-loop. Q/K/V in ONE dispatch.
// Grid locality: fast dim = (n,z) so 18 consecutive blocks share one 196KB
// X-tile and collectively read all of W (hot in L2); XCD-chunked bijective
// remap (m204) gives each XCD a contiguous m-range.
// zi==0 (Q): output pre-scaled by QSF (W and bias scaled).
// zi==2 (V): A=W-frag, B=X-frag so D[m=wcol][n=xrow]; Vt stores become
// 16-lane contiguous 32B runs along Vt's fast (token) dim.
// ---------------------------------------------------------------------------
__global__ __launch_bounds__(256) void proj4u(
    const short* __restrict__ X, const short* __restrict__ Wb,
    const float* __restrict__ bq, const float* __restrict__ bk,
    const float* __restrict__ bv,
    short* __restrict__ Qb, short* __restrict__ Kb, short* __restrict__ Vt)
{
    __shared__ short Xs[2][128 * 32];
    __shared__ short Ws[2][128 * 32];

    int tid = threadIdx.x, lane = tid & 63, wave = tid >> 6;

    // ---- XCD-aware bijective remap: nwg = 18*129 = 2322 = 8*290 + 2 ----
    int lin = blockIdx.x + 18 * blockIdx.y;
    {
        const int q = 290, r = 2;
        int xcd = lin & 7, seq = lin >> 3;
        lin = (xcd < r ? xcd * (q + 1) : r * (q + 1) + (xcd - r) * q) + seq;
    }
    int mblk = lin / 18;
    int nz   = lin - mblk * 18;
    int zi   = nz % 3;          // z fastest
    int nblk = nz / 3;
    bool vsw = (zi == 2);
    const short* W = Wb + (size_t)zi * WSZ;
    int m0 = mblk * 128, n0 = nblk * 128;

    int moff = (wave & 1) * 64, noff = (wave >> 1) * 64;
    int lr = lane & 15, lg = lane >> 4, lk = lg * 8;
    int srow = lane >> 2, sk = (lane & 3) * 8;

    const short* xg0 = X + (size_t)(m0 + wave * 32 + srow) * HID + sk;
    const short* xg1 = xg0 + (size_t)16 * HID;
    const short* wg0 = W + (size_t)(n0 + wave * 32 + srow) * HID + sk;
    const short* wg1 = wg0 + (size_t)16 * HID;

    float4v acc[4][4];
    for (int mi = 0; mi < 4; ++mi)
        for (int ni = 0; ni < 4; ++ni)
            acc[mi][ni] = (float4v){0.f, 0.f, 0.f, 0.f};

#define PSTAGE(bufi, kt) do {                                   \
    gl2lds16(xg0 + (kt) * 32, &Xs[bufi][wave * 1024]);          \
    gl2lds16(xg1 + (kt) * 32, &Xs[bufi][wave * 1024 + 512]);    \
    gl2lds16(wg0 + (kt) * 32, &Ws[bufi][wave * 1024]);          \
    gl2lds16(wg1 + (kt) * 32, &Ws[bufi][wave * 1024 + 512]); } while (0)

    PSTAGE(0, 0);
#pragma unroll
    for (int kt = 0; kt < 24; ++kt) {
        __syncthreads();                     // drains stage(kt); prev compute done
        if (kt < 23) PSTAGE((kt + 1) & 1, kt + 1);
        const short* xb = Xs[kt & 1];
        const short* wb = Ws[kt & 1];
        short8 af[4], bf2[4];
        for (int mi = 0; mi < 4; ++mi)
            af[mi]  = *reinterpret_cast<const short8*>(&xb[(moff + mi * 16 + lr) * 32 + lk]);
        for (int ni = 0; ni < 4; ++ni)
            bf2[ni] = *reinterpret_cast<const short8*>(&wb[(noff + ni * 16 + lr) * 32 + lk]);
        if (!vsw) {
            for (int mi = 0; mi < 4; ++mi)
                for (int ni = 0; ni < 4; ++ni)
                    acc[mi][ni] = __builtin_amdgcn_mfma_f32_16x16x32_bf16(
                        af[mi], bf2[ni], acc[mi][ni], 0, 0, 0);
        } else {
            for (int mi = 0; mi < 4; ++mi)
                for (int ni = 0; ni < 4; ++ni)
                    acc[mi][ni] = __builtin_amdgcn_mfma_f32_16x16x32_bf16(
                        bf2[ni], af[mi], acc[mi][ni], 0, 0, 0);
        }
    }
#undef PSTAGE

    if (!vsw) {
        short* Y = zi == 0 ? Qb : Kb;
        const float* bias = zi == 0 ? bq : bk;
        float bsc = zi == 0 ? QSF : 1.0f;
        for (int ni = 0; ni < 4; ++ni) {
            int gcol = n0 + noff + ni * 16 + lr;
            float bb = bias[gcol] * bsc;
            for (int mi = 0; mi < 4; ++mi) {
                int growb = m0 + moff + mi * 16 + lg * 4;
                for (int r = 0; r < 4; ++r)
                    Y[(size_t)(growb + r) * HID + gcol] = f2bf(acc[mi][ni][r] + bb);
            }
        }
    } else {
        // D[m=wcol = noff+ni*16+lg*4+r][n=xrow = moff+mi*16+lr]
        for (int ni = 0; ni < 4; ++ni) {
            float4 b4 = *reinterpret_cast<const float4*>(&bv[n0 + noff + ni * 16 + lg * 4]);
            const float* bbr = reinterpret_cast<const float*>(&b4);
            for (int mi = 0; mi < 4; ++mi) {
                int grow = m0 + moff + mi * 16 + lr;
                if (grow >= TOT_ROWS) continue;
                int b  = grow >= RPB ? 1 : 0;
                int rb = grow - b * RPB;
                int vr = rb < 33 ? rb : rb + 7;        // doc rows at 40+
                size_t cb = ((size_t)(b * HID + n0 + noff + ni * 16 + lg * 4)) * VT_R;
                for (int r = 0; r < 4; ++r)
                    Vt[cb + (size_t)r * VT_R + vr] = f2bf(acc[mi][ni][r] + bbr[r]);
            }
        }
    }
}

// ---------------------------------------------------------------------------
// Kernel 3: flash attention (S^T form, 128 q/block), double-buffered K/V.
// VALU critical-path diet (round 3):
//  - Q pre-scaled by SCALE*log2e; mask preloaded into the QK^T accumulator
//    => P comes straight out of the MFMA (the 16 v_fma per s are gone).
//  - defer-max check via per-LANE max + __any (v_cmp) — NO cross-lane shfl
//    in the common path; row-max shfls only inside the rare rescale branch.
//  - per-lane partial row-sum lp[s]; cross-lane reduce ONCE in the epilogue
//    (2 shfls total instead of 4 per (kt,s)).
// Token order: doc 0..511, cls 512, query 513..544, pad 545.. (-inf mask).
// ---------------------------------------------------------------------------
__device__ __forceinline__ int row_of(int b, int d, int t) {
    t = t > 544 ? 544 : t;
    int base = b * RPB;
    if (t < 512)  return base + 33 + d * SL + t;
    if (t == 512) return base;
    return base + (t - 512);
}

__global__ __launch_bounds__(256) void attn4(
    const short* __restrict__ Qb, const short* __restrict__ Kb,
    const short* __restrict__ Vt,
    const float* __restrict__ qmask, const float* __restrict__ dmask,
    float* __restrict__ out)
{
    __shared__ short Ks[2][64 * 64];
    __shared__ short Vs[2][64 * 64];
    __shared__ float maskv[576];

    int tid  = threadIdx.x;
    int lane = tid & 63, wave = tid >> 6;

    // ---- XCD-aware remap: nwg = 5*384 = 1920 = 8*240 ----
    int lin = blockIdx.x + 5 * blockIdx.y;
    {
        int xcd = lin & 7, seq = lin >> 3;
        lin = xcd * 240 + seq;
    }
    int hbd = lin / 5;
    int qc  = lin - hbd * 5;
    int h = hbd >> 5, bd = hbd & 31;
    int b = bd >> 4, d = bd & 15;

    int lr = lane & 15, lg = lane >> 4, lk = lg * 8;
    int base = b * RPB;
    const short* vbase = Vt + (size_t)(b * HID + h * HD) * VT_R;

#define ASTAGE(bufi, kt) do {                                               \
    for (int p = 0; p < 2; ++p) {                                           \
        int s2 = p * 256 + tid;                                             \
        int r = s2 >> 3, c = s2 & 7;                                        \
        const short* g = Kb + (size_t)row_of(b, d, (kt) * 64 + r) * HID     \
                       + h * HD + ((c ^ (r & 7)) * 8);                      \
        gl2lds16(g, &Ks[bufi][(p * 256 + (tid & 0xC0)) * 8]);               \
    }                                                                       \
    for (int p = 0; p < 2; ++p) {                                           \
        int s2 = p * 256 + tid;                                             \
        int rd = s2 >> 3, c = s2 & 7;                                       \
        int tc = (kt) * 64 + ((c ^ (rd & 7)) * 8);                          \
        int vr = tc < 512 ? 40 + d * SL + tc : tc - 512;                    \
        gl2lds16(vbase + (size_t)rd * VT_R + vr,                            \
                 &Vs[bufi][(p * 256 + (tid & 0xC0)) * 8]);                  \
    } } while (0)

    ASTAGE(0, 0);

    for (int i = tid; i < 576; i += 256) {
        float mv;
        if (i < 512)       mv = dmask[(size_t)(b * D_ + d) * SL + i];
        else if (i == 512) mv = 0.f;
        else if (i < 545)  mv = qmask[b * QL + (i - 513)];
        else               mv = -INFINITY;
        maskv[i] = mv * LOG2E;
    }

    short8 bq0[2], bq1[2];
    for (int s = 0; s < 2; ++s) {
        int qtok = qc * 128 + s * 64 + wave * 16 + lr;
        int qrow = qtok < 512 ? base + 33 + d * SL + qtok : base + qtok - 512;
        const short* qp = Qb + (size_t)qrow * HID + h * HD + lk;
        bq0[s] = *reinterpret_cast<const short8*>(qp);
        bq1[s] = *reinterpret_cast<const short8*>(qp + 32);
    }

    float m_i[2] = {-1e30f, -1e30f};
    float lp[2]  = {0.f, 0.f};          // per-LANE partial row sums
    float4v o[2][4];
    for (int s = 0; s < 2; ++s)
        for (int nt = 0; nt < 4; ++nt) o[s][nt] = (float4v){0.f, 0.f, 0.f, 0.f};

#pragma unroll
    for (int kt = 0; kt < 9; ++kt) {
        __syncthreads();                    // stage(kt) drained; prev compute done
        if (kt < 8) ASTAGE((kt + 1) & 1, kt + 1);
        const short* kb = Ks[kt & 1];
        const short* vbuf = Vs[kt & 1];

        short8 kf0[4], kf1[4];
        for (int nt = 0; nt < 4; ++nt) {
            int r = nt * 16 + lr;
            int x0 = lg ^ (r & 7);
            kf0[nt] = *reinterpret_cast<const short8*>(&kb[r * 64 + x0 * 8]);
            kf1[nt] = *reinterpret_cast<const short8*>(&kb[r * 64 + (x0 ^ 4) * 8]);
        }

        for (int s = 0; s < 2; ++s) {
            // ---- QK^T: lane holds P[key = kt*64+nt*16+lg*4+r][q = lr];
            //      mask pre-loaded into the accumulator, Q pre-scaled ----
            float p4[4][4];
            __builtin_amdgcn_s_setprio(1);
            for (int nt = 0; nt < 4; ++nt) {
                float4v z = *reinterpret_cast<const float4v*>(
                    &maskv[kt * 64 + nt * 16 + lg * 4]);
                z = __builtin_amdgcn_mfma_f32_16x16x32_bf16(kf0[nt], bq0[s], z, 0, 0, 0);
                z = __builtin_amdgcn_mfma_f32_16x16x32_bf16(kf1[nt], bq1[s], z, 0, 0, 0);
                for (int r = 0; r < 4; ++r) p4[nt][r] = z[r];
            }
            __builtin_amdgcn_s_setprio(0);

            // ---- per-LANE max (max3-fusable); no cross-lane in common path ----
            float c0 = fmaxf(fmaxf(p4[0][0], p4[0][1]), p4[0][2]);
            float c1 = fmaxf(fmaxf(p4[0][3], p4[1][0]), p4[1][1]);
            float c2 = fmaxf(fmaxf(p4[1][2], p4[1][3]), p4[2][0]);
            float c3 = fmaxf(fmaxf(p4[2][1], p4[2][2]), p4[2][3]);
            float c4 = fmaxf(fmaxf(p4[3][0], p4[3][1]), p4[3][2]);
            float lmax = fmaxf(fmaxf(fmaxf(c0, c1), fmaxf(c2, c3)),
                               fmaxf(c4, p4[3][3]));

            // ---- defer-max: rescale only if some row grows past m+8 ----
            if (__any(lmax > m_i[s] + 8.0f)) {
                float tmx = fmaxf(lmax, __shfl_xor(lmax, 16));
                tmx = fmaxf(tmx, __shfl_xor(tmx, 32));       // row max (q=lr)
                float mnew = fmaxf(m_i[s], tmx);
                float alpha = exp2f(m_i[s] - mnew);
                m_i[s] = mnew;
                lp[s] *= alpha;
                float al[4];
                for (int r = 0; r < 4; ++r) al[r] = __shfl(alpha, lg * 4 + r);
                for (int nt = 0; nt < 4; ++nt)
                    for (int r = 0; r < 4; ++r) o[s][nt][r] *= al[r];
            }

            // ---- exp2 + per-lane partial sum (P bounded by 2^8) ----
            for (int nt = 0; nt < 4; ++nt)
                for (int r = 0; r < 4; ++r)
                    p4[nt][r] = exp2f(p4[nt][r] - m_i[s]);
            float s0 = (p4[0][0] + p4[0][1]) + (p4[0][2] + p4[0][3]);
            float s1 = (p4[1][0] + p4[1][1]) + (p4[1][2] + p4[1][3]);
            float s2 = (p4[2][0] + p4[2][1]) + (p4[2][2] + p4[2][3]);
            float s3 = (p4[3][0] + p4[3][1]) + (p4[3][2] + p4[3][3]);
            lp[s] += (s0 + s1) + (s2 + s3);

            // ---- in-register P -> PV A-fragment repack ----
            unsigned int wa[4], wbv[4];
            for (int nt = 0; nt < 4; ++nt) {
                wa[nt]  = cvtpk(p4[nt][0], p4[nt][1]);
                wbv[nt] = cvtpk(p4[nt][2], p4[nt][3]);
            }
            uint2v tA01 = __builtin_amdgcn_permlane32_swap(wa[0],  wa[1],  false, false);
            uint2v uA01 = __builtin_amdgcn_permlane16_swap(tA01[0], tA01[1], false, false);
            uint2v tB01 = __builtin_amdgcn_permlane32_swap(wbv[0], wbv[1], false, false);
            uint2v uB01 = __builtin_amdgcn_permlane16_swap(tB01[0], tB01[1], false, false);
            uint2v tA23 = __builtin_amdgcn_permlane32_swap(wa[2],  wa[3],  false, false);
            uint2v uA23 = __builtin_amdgcn_permlane16_swap(tA23[0], tA23[1], false, false);
            uint2v tB23 = __builtin_amdgcn_permlane32_swap(wbv[2], wbv[3], false, false);
            uint2v uB23 = __builtin_amdgcn_permlane16_swap(tB23[0], tB23[1], false, false);

            union { unsigned int u[4]; short8 s8; } A0, A1;
            A0.u[0] = uA01[0]; A0.u[1] = uB01[0]; A0.u[2] = uA01[1]; A0.u[3] = uB01[1];
            A1.u[0] = uA23[0]; A1.u[1] = uB23[0]; A1.u[2] = uA23[1]; A1.u[3] = uB23[1];
            short8 ap0 = A0.s8;
            short8 ap1 = A1.s8;

            // ---- PV ----
            __builtin_amdgcn_s_setprio(1);
            for (int nt = 0; nt < 4; ++nt) {
                int rd = nt * 16 + lr;
                int x0 = lg ^ (rd & 7);
                short8 bv0 = *reinterpret_cast<const short8*>(&vbuf[rd * 64 + x0 * 8]);
                short8 bv1 = *reinterpret_cast<const short8*>(&vbuf[rd * 64 + (x0 ^ 4) * 8]);
                o[s][nt] = __builtin_amdgcn_mfma_f32_16x16x32_bf16(ap0, bv0, o[s][nt], 0, 0, 0);
                o[s][nt] = __builtin_amdgcn_mfma_f32_16x16x32_bf16(ap1, bv1, o[s][nt], 0, 0, 0);
            }
            __builtin_amdgcn_s_setprio(0);
        }
    }
#undef ASTAGE

    for (int s = 0; s < 2; ++s) {
        float lt = lp[s];
        lt += __shfl_xor(lt, 16);
        lt += __shfl_xor(lt, 32);           // row total (q=lr), replicated
        float li[4];
        for (int r = 0; r < 4; ++r) li[r] = __shfl(lt, lg * 4 + r);
        for (int r = 0; r < 4; ++r) {
            int t = qc * 128 + s * 64 + wave * 16 + lg * 4 + r;
            if (t >= SEQ) continue;
            int seq = t < 512 ? 33 + t : (t == 512 ? 0 : t - 512);
            float inv = 1.f / li[r];
            float* op = out + ((size_t)(bd * SEQ + seq)) * HID + h * HD + lr;
            for (int nt = 0; nt < 4; ++nt)
                op[nt * 16] = o[s][nt][r] * inv;
        }
    }
}

// ---------------------------------------------------------------------------
extern "C" void kernel_launch(void* const* d_in, const int* in_sizes, int n_in,
                              void* d_out, int out_size, void* d_ws, size_t ws_size,
                              hipStream_t stream)
{
    const float* cls   = (const float*)d_in[0];
    const float* query = (const float*)d_in[1];
    const float* doc   = (const float*)d_in[2];
    const float* qmask = (const float*)d_in[3];
    const float* dmask = (const float*)d_in[4];
    const float* Wq = (const float*)d_in[5];
    const float* bq = (const float*)d_in[6];
    const float* Wk = (const float*)d_in[7];
    const float* bk = (const float*)d_in[8];
    const float* Wv = (const float*)d_in[9];
    const float* bv = (const float*)d_in[10];
    float* out = (float*)d_out;

    short* X  = (short*)d_ws;
    size_t seg = (size_t)PAD_ROWS * HID;
    short* Qb = X + seg;
    short* Kb = Qb + seg;
    short* Vt = Kb + seg;                 // 2*768*8256 == seg
    short* Wb = (short*)d_out;            // scratch; attn4 overwrites all of out

    pack_all<<<dim3(PACK_BLKS + WPACK_BLKS), 256, 0, stream>>>(
        cls, query, doc, Wq, Wk, Wv, X, Wb);
    proj4u<<<dim3(18, 129, 1), 256, 0, stream>>>(X, Wb, bq, bk, bv, Qb, Kb, Vt);
    attn4<<<dim3(5, NH * 32, 1), 256, 0, stream>>>(Qb, Kb, Vt, qmask, dmask, out);
}

// Round 4
// 285.438 us; speedup vs baseline: 1.2077x; 1.0656x over previous
//
#include <hip/hip_runtime.h>
#include <hip/hip_bf16.h>

#define NH      12
#define HD      64
#define HID     768
#define B_      2
#define D_      16
#define QL      32
#define SL      512
#define SEQ     545
#define RPB     8225
#define TOT_ROWS 16450
#define PAD_ROWS 16512       // 129*128
#define VT_R    8256         // Vt rows/batch: cls=0, query 1..32, doc d at 40+d*512
#define WSZ     589824       // 768*768
#define SCALE_  0.125f
#define LOG2E   1.4426950408889634f
#define QSF     0.18033688011112042f   // SCALE_*LOG2E, folded into Wq/bq

typedef __attribute__((ext_vector_type(8))) short short8;
typedef __attribute__((ext_vector_type(4))) short short4v;
typedef __attribute__((ext_vector_type(4))) float float4v;
typedef __attribute__((ext_vector_type(2))) unsigned int uint2v;

__device__ __forceinline__ short f2bf(float f) {
    __hip_bfloat16 h = __float2bfloat16(f);
    short s; __builtin_memcpy(&s, &h, 2);
    return s;
}

// v_cvt_pk_bf16_f32: lo16=bf16(a), hi16=bf16(b) — no builtin on gfx950
__device__ __forceinline__ unsigned int cvtpk(float a, float b) {
    unsigned int r;
    asm("v_cvt_pk_bf16_f32 %0, %1, %2" : "=v"(r) : "v"(a), "v"(b));
    return r;
}

// async global->LDS 16B/lane; lds base wave-uniform (HW adds lane*16)
__device__ __forceinline__ void gl2lds16(const short* g, short* l) {
    __builtin_amdgcn_global_load_lds(
        (const __attribute__((address_space(1))) void*)g,
        (__attribute__((address_space(3))) void*)l, 16, 0, 0);
}

#define PACK_BLKS  12384     // PAD_ROWS*HID/4/256
#define WPACK_BLKS 1728      // 3*WSZ/4/256

// ---------------------------------------------------------------------------
// Kernel 1 (fused): gather cls/query/doc fp32 -> bf16 X [PAD_ROWS x 768],
// and W fp32 -> bf16 (Wq pre-scaled by SCALE*log2e; Wb parked in d_out).
// ---------------------------------------------------------------------------
__global__ __launch_bounds__(256) void pack_all(
    const float* __restrict__ cls, const float* __restrict__ query,
    const float* __restrict__ doc,
    const float* __restrict__ Wq, const float* __restrict__ Wk,
    const float* __restrict__ Wv,
    short* __restrict__ X, short* __restrict__ Wb)
{
    int bid = blockIdx.x;
    if (bid < PACK_BLKS) {
        int idx = (bid * 256 + threadIdx.x) * 4;
        int row = idx / HID;
        int col = idx - row * HID;
        float4 v = make_float4(0.f, 0.f, 0.f, 0.f);
        if (row < TOT_ROWS) {
            int b = row / RPB;
            int r = row - b * RPB;
            const float* src;
            if (r == 0)        src = cls   + b * HID + col;
            else if (r < 33)   src = query + ((size_t)(b * QL + (r - 1))) * HID + col;
            else               src = doc   + ((size_t)(b * (D_ * SL) + (r - 33))) * HID + col;
            v = *reinterpret_cast<const float4*>(src);
        }
        short4v o;
        o[0] = f2bf(v.x); o[1] = f2bf(v.y); o[2] = f2bf(v.z); o[3] = f2bf(v.w);
        *reinterpret_cast<short4v*>(X + idx) = o;
    } else {
        int idx = ((bid - PACK_BLKS) * 256 + threadIdx.x) * 4;
        int z = idx / WSZ;
        int r = idx - z * WSZ;
        const float* src = (z == 0 ? Wq : (z == 1 ? Wk : Wv)) + r;
        float sc = (z == 0) ? QSF : 1.0f;   // fold qk-scale*log2e into Wq
        float4 v = *reinterpret_cast<const float4*>(src);
        short4v o;
        o[0] = f2bf(v.x * sc); o[1] = f2bf(v.y * sc);
        o[2] = f2bf(v.z * sc); o[3] = f2bf(v.w * sc);
        *reinterpret_cast<short4v*>(Wb + idx) = o;
    }
}

// ---------------------------------------------------------------------------
// Kernel 2: projection GEMM, 128x128 tile, BK=64 (12 K-steps), single-barrier
// double-buffered K-loop. Q/K/V in ONE dispatch.
// BK=64 rationale: occupancy is register-capped at 2 blocks/CU (64-AGPR acc),
// so 64KB LDS costs nothing; halving the barrier count doubles the compute
// window that covers each global_load_lds drain (latency-bound fix).
// LDS rows are 128B => XOR chunk swizzle (c ^ (row&7), same as attn ASTAGE):
// ds_read_b128 becomes 2-way (free) instead of 8-lanes-on-4-banks.
// Grid locality: fast dim = (n,z); XCD-chunked bijective remap (m204).
// zi==0 (Q): output pre-scaled by QSF (W and bias scaled).
// zi==2 (V): A=W-frag, B=X-frag so D[m=wcol][n=xrow]; Vt stores become
// 16-lane contiguous 32B runs along Vt's fast (token) dim.
// ---------------------------------------------------------------------------
__global__ __launch_bounds__(256) void proj4u(
    const short* __restrict__ X, const short* __restrict__ Wb,
    const float* __restrict__ bq, const float* __restrict__ bk,
    const float* __restrict__ bv,
    short* __restrict__ Qb, short* __restrict__ Kb, short* __restrict__ Vt)
{
    __shared__ short Xs[2][128 * 64];
    __shared__ short Ws[2][128 * 64];

    int tid = threadIdx.x, lane = tid & 63, wave = tid >> 6;

    // ---- XCD-aware bijective remap: nwg = 18*129 = 2322 = 8*290 + 2 ----
    int lin = blockIdx.x + 18 * blockIdx.y;
    {
        const int q = 290, r = 2;
        int xcd = lin & 7, seq = lin >> 3;
        lin = (xcd < r ? xcd * (q + 1) : r * (q + 1) + (xcd - r) * q) + seq;
    }
    int mblk = lin / 18;
    int nz   = lin - mblk * 18;
    int zi   = nz % 3;          // z fastest
    int nblk = nz / 3;
    bool vsw = (zi == 2);
    const short* W = Wb + (size_t)zi * WSZ;
    int m0 = mblk * 128, n0 = nblk * 128;

    int moff = (wave & 1) * 64, noff = (wave >> 1) * 64;
    int lr = lane & 15, lg = lane >> 4;

    // staging sources: slot s = p*256+tid -> row = s>>3, chunk c = s&7;
    // position c in LDS holds logical chunk (c ^ (row&7)) of the 64-K window.
    const short* xsrc[4];
    const short* wsrc[4];
#pragma unroll
    for (int p = 0; p < 4; ++p) {
        int s = p * 256 + tid;
        int row = s >> 3, c = s & 7;
        int col = (c ^ (row & 7)) * 8;
        xsrc[p] = X + (size_t)(m0 + row) * HID + col;
        wsrc[p] = W + (size_t)(n0 + row) * HID + col;
    }

    float4v acc[4][4];
    for (int mi = 0; mi < 4; ++mi)
        for (int ni = 0; ni < 4; ++ni)
            acc[mi][ni] = (float4v){0.f, 0.f, 0.f, 0.f};

#define PSTAGE(bufi, kt) do {                                               \
    _Pragma("unroll")                                                       \
    for (int p = 0; p < 4; ++p) {                                           \
        gl2lds16(xsrc[p] + (kt) * 64,                                       \
                 &Xs[bufi][(p * 256 + (tid & 0xC0)) * 8]);                  \
        gl2lds16(wsrc[p] + (kt) * 64,                                       \
                 &Ws[bufi][(p * 256 + (tid & 0xC0)) * 8]);                  \
    } } while (0)

    PSTAGE(0, 0);
#pragma unroll
    for (int kt = 0; kt < 12; ++kt) {
        __syncthreads();                     // drains stage(kt); prev compute done
        if (kt < 11) PSTAGE((kt + 1) & 1, kt + 1);
        const short* xb = Xs[kt & 1];
        const short* wb = Ws[kt & 1];
        short8 afl[4], afh[4], bfl[4], bfh[4];
        for (int mi = 0; mi < 4; ++mi) {
            int r = moff + mi * 16 + lr;
            int x0 = lg ^ (r & 7);
            afl[mi] = *reinterpret_cast<const short8*>(&xb[r * 64 + x0 * 8]);
            afh[mi] = *reinterpret_cast<const short8*>(&xb[r * 64 + (x0 ^ 4) * 8]);
        }
        for (int ni = 0; ni < 4; ++ni) {
            int r = noff + ni * 16 + lr;
            int x0 = lg ^ (r & 7);
            bfl[ni] = *reinterpret_cast<const short8*>(&wb[r * 64 + x0 * 8]);
            bfh[ni] = *reinterpret_cast<const short8*>(&wb[r * 64 + (x0 ^ 4) * 8]);
        }
        if (!vsw) {
            for (int mi = 0; mi < 4; ++mi)
                for (int ni = 0; ni < 4; ++ni) {
                    acc[mi][ni] = __builtin_amdgcn_mfma_f32_16x16x32_bf16(
                        afl[mi], bfl[ni], acc[mi][ni], 0, 0, 0);
                    acc[mi][ni] = __builtin_amdgcn_mfma_f32_16x16x32_bf16(
                        afh[mi], bfh[ni], acc[mi][ni], 0, 0, 0);
                }
        } else {
            for (int mi = 0; mi < 4; ++mi)
                for (int ni = 0; ni < 4; ++ni) {
                    acc[mi][ni] = __builtin_amdgcn_mfma_f32_16x16x32_bf16(
                        bfl[ni], afl[mi], acc[mi][ni], 0, 0, 0);
                    acc[mi][ni] = __builtin_amdgcn_mfma_f32_16x16x32_bf16(
                        bfh[ni], afh[mi], acc[mi][ni], 0, 0, 0);
                }
        }
    }
#undef PSTAGE

    if (!vsw) {
        short* Y = zi == 0 ? Qb : Kb;
        const float* bias = zi == 0 ? bq : bk;
        float bsc = zi == 0 ? QSF : 1.0f;
        for (int ni = 0; ni < 4; ++ni) {
            int gcol = n0 + noff + ni * 16 + lr;
            float bb = bias[gcol] * bsc;
            for (int mi = 0; mi < 4; ++mi) {
                int growb = m0 + moff + mi * 16 + lg * 4;
                for (int r = 0; r < 4; ++r)
                    Y[(size_t)(growb + r) * HID + gcol] = f2bf(acc[mi][ni][r] + bb);
            }
        }
    } else {
        // D[m=wcol = noff+ni*16+lg*4+r][n=xrow = moff+mi*16+lr]
        for (int ni = 0; ni < 4; ++ni) {
            float4 b4 = *reinterpret_cast<const float4*>(&bv[n0 + noff + ni * 16 + lg * 4]);
            const float* bbr = reinterpret_cast<const float*>(&b4);
            for (int mi = 0; mi < 4; ++mi) {
                int grow = m0 + moff + mi * 16 + lr;
                if (grow >= TOT_ROWS) continue;
                int b  = grow >= RPB ? 1 : 0;
                int rb = grow - b * RPB;
                int vr = rb < 33 ? rb : rb + 7;        // doc rows at 40+
                size_t cb = ((size_t)(b * HID + n0 + noff + ni * 16 + lg * 4)) * VT_R;
                for (int r = 0; r < 4; ++r)
                    Vt[cb + (size_t)r * VT_R + vr] = f2bf(acc[mi][ni][r] + bbr[r]);
            }
        }
    }
}

// ---------------------------------------------------------------------------
// Kernel 3: flash attention (S^T form, 128 q/block), double-buffered K/V.
//  - Q pre-scaled by SCALE*log2e; mask preloaded into the QK^T accumulator.
//  - defer-max check via per-LANE max + __any; row-max shfls only in the
//    rare rescale branch; per-lane partial row-sum, reduced in the epilogue.
//  - in-register P->A-fragment repack (cvt_pk + permlane).
// Token order: doc 0..511, cls 512, query 513..544, pad 545.. (-inf mask).
// ---------------------------------------------------------------------------
__device__ __forceinline__ int row_of(int b, int d, int t) {
    t = t > 544 ? 544 : t;
    int base = b * RPB;
    if (t < 512)  return base + 33 + d * SL + t;
    if (t == 512) return base;
    return base + (t - 512);
}

__global__ __launch_bounds__(256) void attn4(
    const short* __restrict__ Qb, const short* __restrict__ Kb,
    const short* __restrict__ Vt,
    const float* __restrict__ qmask, const float* __restrict__ dmask,
    float* __restrict__ out)
{
    __shared__ short Ks[2][64 * 64];
    __shared__ short Vs[2][64 * 64];
    __shared__ float maskv[576];

    int tid  = threadIdx.x;
    int lane = tid & 63, wave = tid >> 6;

    // ---- XCD-aware remap: nwg = 5*384 = 1920 = 8*240 ----
    int lin = blockIdx.x + 5 * blockIdx.y;
    {
        int xcd = lin & 7, seq = lin >> 3;
        lin = xcd * 240 + seq;
    }
    int hbd = lin / 5;
    int qc  = lin - hbd * 5;
    int h = hbd >> 5, bd = hbd & 31;
    int b = bd >> 4, d = bd & 15;

    int lr = lane & 15, lg = lane >> 4, lk = lg * 8;
    int base = b * RPB;
    const short* vbase = Vt + (size_t)(b * HID + h * HD) * VT_R;

#define ASTAGE(bufi, kt) do {                                               \
    for (int p = 0; p < 2; ++p) {                                           \
        int s2 = p * 256 + tid;                                             \
        int r = s2 >> 3, c = s2 & 7;                                        \
        const short* g = Kb + (size_t)row_of(b, d, (kt) * 64 + r) * HID     \
                       + h * HD + ((c ^ (r & 7)) * 8);                      \
        gl2lds16(g, &Ks[bufi][(p * 256 + (tid & 0xC0)) * 8]);               \
    }                                                                       \
    for (int p = 0; p < 2; ++p) {                                           \
        int s2 = p * 256 + tid;                                             \
        int rd = s2 >> 3, c = s2 & 7;                                       \
        int tc = (kt) * 64 + ((c ^ (rd & 7)) * 8);                          \
        int vr = tc < 512 ? 40 + d * SL + tc : tc - 512;                    \
        gl2lds16(vbase + (size_t)rd * VT_R + vr,                            \
                 &Vs[bufi][(p * 256 + (tid & 0xC0)) * 8]);                  \
    } } while (0)

    ASTAGE(0, 0);

    for (int i = tid; i < 576; i += 256) {
        float mv;
        if (i < 512)       mv = dmask[(size_t)(b * D_ + d) * SL + i];
        else if (i == 512) mv = 0.f;
        else if (i < 545)  mv = qmask[b * QL + (i - 513)];
        else               mv = -INFINITY;
        maskv[i] = mv * LOG2E;
    }

    short8 bq0[2], bq1[2];
    for (int s = 0; s < 2; ++s) {
        int qtok = qc * 128 + s * 64 + wave * 16 + lr;
        int qrow = qtok < 512 ? base + 33 + d * SL + qtok : base + qtok - 512;
        const short* qp = Qb + (size_t)qrow * HID + h * HD + lk;
        bq0[s] = *reinterpret_cast<const short8*>(qp);
        bq1[s] = *reinterpret_cast<const short8*>(qp + 32);
    }

    float m_i[2] = {-1e30f, -1e30f};
    float lp[2]  = {0.f, 0.f};          // per-LANE partial row sums
    float4v o[2][4];
    for (int s = 0; s < 2; ++s)
        for (int nt = 0; nt < 4; ++nt) o[s][nt] = (float4v){0.f, 0.f, 0.f, 0.f};

#pragma unroll
    for (int kt = 0; kt < 9; ++kt) {
        __syncthreads();                    // stage(kt) drained; prev compute done
        if (kt < 8) ASTAGE((kt + 1) & 1, kt + 1);
        const short* kb = Ks[kt & 1];
        const short* vbuf = Vs[kt & 1];

        short8 kf0[4], kf1[4];
        for (int nt = 0; nt < 4; ++nt) {
            int r = nt * 16 + lr;
            int x0 = lg ^ (r & 7);
            kf0[nt] = *reinterpret_cast<const short8*>(&kb[r * 64 + x0 * 8]);
            kf1[nt] = *reinterpret_cast<const short8*>(&kb[r * 64 + (x0 ^ 4) * 8]);
        }

        for (int s = 0; s < 2; ++s) {
            // ---- QK^T: lane holds P[key = kt*64+nt*16+lg*4+r][q = lr];
            //      mask pre-loaded into the accumulator, Q pre-scaled ----
            float p4[4][4];
            __builtin_amdgcn_s_setprio(1);
            for (int nt = 0; nt < 4; ++nt) {
                float4v z = *reinterpret_cast<const float4v*>(
                    &maskv[kt * 64 + nt * 16 + lg * 4]);
                z = __builtin_amdgcn_mfma_f32_16x16x32_bf16(kf0[nt], bq0[s], z, 0, 0, 0);
                z = __builtin_amdgcn_mfma_f32_16x16x32_bf16(kf1[nt], bq1[s], z, 0, 0, 0);
                for (int r = 0; r < 4; ++r) p4[nt][r] = z[r];
            }
            __builtin_amdgcn_s_setprio(0);

            // ---- per-LANE max (max3-fusable); no cross-lane in common path ----
            float c0 = fmaxf(fmaxf(p4[0][0], p4[0][1]), p4[0][2]);
            float c1 = fmaxf(fmaxf(p4[0][3], p4[1][0]), p4[1][1]);
            float c2 = fmaxf(fmaxf(p4[1][2], p4[1][3]), p4[2][0]);
            float c3 = fmaxf(fmaxf(p4[2][1], p4[2][2]), p4[2][3]);
            float c4 = fmaxf(fmaxf(p4[3][0], p4[3][1]), p4[3][2]);
            float lmax = fmaxf(fmaxf(fmaxf(c0, c1), fmaxf(c2, c3)),
                               fmaxf(c4, p4[3][3]));

            // ---- defer-max: rescale only if some row grows past m+8 ----
            if (__any(lmax > m_i[s] + 8.0f)) {
                float tmx = fmaxf(lmax, __shfl_xor(lmax, 16));
                tmx = fmaxf(tmx, __shfl_xor(tmx, 32));       // row max (q=lr)
                float mnew = fmaxf(m_i[s], tmx);
                float alpha = exp2f(m_i[s] - mnew);
                m_i[s] = mnew;
                lp[s] *= alpha;
                float al[4];
                for (int r = 0; r < 4; ++r) al[r] = __shfl(alpha, lg * 4 + r);
                for (int nt = 0; nt < 4; ++nt)
                    for (int r = 0; r < 4; ++r) o[s][nt][r] *= al[r];
            }

            // ---- exp2 + per-lane partial sum (P bounded by 2^8) ----
            for (int nt = 0; nt < 4; ++nt)
                for (int r = 0; r < 4; ++r)
                    p4[nt][r] = exp2f(p4[nt][r] - m_i[s]);
            float s0 = (p4[0][0] + p4[0][1]) + (p4[0][2] + p4[0][3]);
            float s1 = (p4[1][0] + p4[1][1]) + (p4[1][2] + p4[1][3]);
            float s2 = (p4[2][0] + p4[2][1]) + (p4[2][2] + p4[2][3]);
            float s3 = (p4[3][0] + p4[3][1]) + (p4[3][2] + p4[3][3]);
            lp[s] += (s0 + s1) + (s2 + s3);

            // ---- in-register P -> PV A-fragment repack ----
            unsigned int wa[4], wbv[4];
            for (int nt = 0; nt < 4; ++nt) {
                wa[nt]  = cvtpk(p4[nt][0], p4[nt][1]);
                wbv[nt] = cvtpk(p4[nt][2], p4[nt][3]);
            }
            uint2v tA01 = __builtin_amdgcn_permlane32_swap(wa[0],  wa[1],  false, false);
            uint2v uA01 = __builtin_amdgcn_permlane16_swap(tA01[0], tA01[1], false, false);
            uint2v tB01 = __builtin_amdgcn_permlane32_swap(wbv[0], wbv[1], false, false);
            uint2v uB01 = __builtin_amdgcn_permlane16_swap(tB01[0], tB01[1], false, false);
            uint2v tA23 = __builtin_amdgcn_permlane32_swap(wa[2],  wa[3],  false, false);
            uint2v uA23 = __builtin_amdgcn_permlane16_swap(tA23[0], tA23[1], false, false);
            uint2v tB23 = __builtin_amdgcn_permlane32_swap(wbv[2], wbv[3], false, false);
            uint2v uB23 = __builtin_amdgcn_permlane16_swap(tB23[0], tB23[1], false, false);

            union { unsigned int u[4]; short8 s8; } A0, A1;
            A0.u[0] = uA01[0]; A0.u[1] = uB01[0]; A0.u[2] = uA01[1]; A0.u[3] = uB01[1];
            A1.u[0] = uA23[0]; A1.u[1] = uB23[0]; A1.u[2] = uA23[1]; A1.u[3] = uB23[1];
            short8 ap0 = A0.s8;
            short8 ap1 = A1.s8;

            // ---- PV ----
            __builtin_amdgcn_s_setprio(1);
            for (int nt = 0; nt < 4; ++nt) {
                int rd = nt * 16 + lr;
                int x0 = lg ^ (rd & 7);
                short8 bv0 = *reinterpret_cast<const short8*>(&vbuf[rd * 64 + x0 * 8]);
                short8 bv1 = *reinterpret_cast<const short8*>(&vbuf[rd * 64 + (x0 ^ 4) * 8]);
                o[s][nt] = __builtin_amdgcn_mfma_f32_16x16x32_bf16(ap0, bv0, o[s][nt], 0, 0, 0);
                o[s][nt] = __builtin_amdgcn_mfma_f32_16x16x32_bf16(ap1, bv1, o[s][nt], 0, 0, 0);
            }
            __builtin_amdgcn_s_setprio(0);
        }
    }
#undef ASTAGE

    for (int s = 0; s < 2; ++s) {
        float lt = lp[s];
        lt += __shfl_xor(lt, 16);
        lt += __shfl_xor(lt, 32);           // row total (q=lr), replicated
        float li[4];
        for (int r = 0; r < 4; ++r) li[r] = __shfl(lt, lg * 4 + r);
        for (int r = 0; r < 4; ++r) {
            int t = qc * 128 + s * 64 + wave * 16 + lg * 4 + r;
            if (t >= SEQ) continue;
            int seq = t < 512 ? 33 + t : (t == 512 ? 0 : t - 512);
            float inv = 1.f / li[r];
            float* op = out + ((size_t)(bd * SEQ + seq)) * HID + h * HD + lr;
            for (int nt = 0; nt < 4; ++nt)
                op[nt * 16] = o[s][nt][r] * inv;
        }
    }
}

// ---------------------------------------------------------------------------
extern "C" void kernel_launch(void* const* d_in, const int* in_sizes, int n_in,
                              void* d_out, int out_size, void* d_ws, size_t ws_size,
                              hipStream_t stream)
{
    const float* cls   = (const float*)d_in[0];
    const float* query = (const float*)d_in[1];
    const float* doc   = (const float*)d_in[2];
    const float* qmask = (const float*)d_in[3];
    const float* dmask = (const float*)d_in[4];
    const float* Wq = (const float*)d_in[5];
    const float* bq = (const float*)d_in[6];
    const float* Wk = (const float*)d_in[7];
    const float* bk = (const float*)d_in[8];
    const float* Wv = (const float*)d_in[9];
    const float* bv = (const float*)d_in[10];
    float* out = (float*)d_out;

    short* X  = (short*)d_ws;
    size_t seg = (size_t)PAD_ROWS * HID;
    short* Qb = X + seg;
    short* Kb = Qb + seg;
    short* Vt = Kb + seg;                 // 2*768*8256 == seg
    short* Wb = (short*)d_out;            // scratch; attn4 overwrites all of out

    pack_all<<<dim3(PACK_BLKS + WPACK_BLKS), 256, 0, stream>>>(
        cls, query, doc, Wq, Wk, Wv, X, Wb);
    proj4u<<<dim3(18, 129, 1), 256, 0, stream>>>(X, Wb, bq, bk, bv, Qb, Kb, Vt);
    attn4<<<dim3(5, NH * 32, 1), 256, 0, stream>>>(Qb, Kb, Vt, qmask, dmask, out);
}

// Round 5
// 278.280 us; speedup vs baseline: 1.2388x; 1.0257x over previous
//
#include <hip/hip_runtime.h>
#include <hip/hip_bf16.h>

#define NH      12
#define HD      64
#define HID     768
#define B_      2
#define D_      16
#define QL      32
#define SL      512
#define SEQ     545
#define RPB     8225
#define TOT_ROWS 16450
#define PAD_ROWS 16512       // 129*128
#define VT_R    8256         // Vt rows/batch: cls=0, query 1..32, doc d at 40+d*512
#define WSZ     589824       // 768*768
#define SCALE_  0.125f
#define LOG2E   1.4426950408889634f
#define QSF     0.18033688011112042f   // SCALE_*LOG2E, folded into Wq/bq

typedef __attribute__((ext_vector_type(8))) short short8;
typedef __attribute__((ext_vector_type(4))) short short4v;
typedef __attribute__((ext_vector_type(4))) float float4v;
typedef __attribute__((ext_vector_type(2))) unsigned int uint2v;

__device__ __forceinline__ short f2bf(float f) {
    __hip_bfloat16 h = __float2bfloat16(f);
    short s; __builtin_memcpy(&s, &h, 2);
    return s;
}

// v_cvt_pk_bf16_f32: lo16=bf16(a), hi16=bf16(b) — no builtin on gfx950
__device__ __forceinline__ unsigned int cvtpk(float a, float b) {
    unsigned int r;
    asm("v_cvt_pk_bf16_f32 %0, %1, %2" : "=v"(r) : "v"(a), "v"(b));
    return r;
}

// async global->LDS 16B/lane; lds base wave-uniform (HW adds lane*16)
__device__ __forceinline__ void gl2lds16(const short* g, short* l) {
    __builtin_amdgcn_global_load_lds(
        (const __attribute__((address_space(1))) void*)g,
        (__attribute__((address_space(3))) void*)l, 16, 0, 0);
}

#define PACK_BLKS  12384     // PAD_ROWS*HID/4/256
#define WPACK_BLKS 1728      // 3*WSZ/4/256

// ---------------------------------------------------------------------------
// Kernel 1 (fused): gather cls/query/doc fp32 -> bf16 X [PAD_ROWS x 768],
// and W fp32 -> bf16 (Wq pre-scaled by SCALE*log2e; Wb parked in d_out).
// ---------------------------------------------------------------------------
__global__ __launch_bounds__(256) void pack_all(
    const float* __restrict__ cls, const float* __restrict__ query,
    const float* __restrict__ doc,
    const float* __restrict__ Wq, const float* __restrict__ Wk,
    const float* __restrict__ Wv,
    short* __restrict__ X, short* __restrict__ Wb)
{
    int bid = blockIdx.x;
    if (bid < PACK_BLKS) {
        int idx = (bid * 256 + threadIdx.x) * 4;
        int row = idx / HID;
        int col = idx - row * HID;
        float4 v = make_float4(0.f, 0.f, 0.f, 0.f);
        if (row < TOT_ROWS) {
            int b = row / RPB;
            int r = row - b * RPB;
            const float* src;
            if (r == 0)        src = cls   + b * HID + col;
            else if (r < 33)   src = query + ((size_t)(b * QL + (r - 1))) * HID + col;
            else               src = doc   + ((size_t)(b * (D_ * SL) + (r - 33))) * HID + col;
            v = *reinterpret_cast<const float4*>(src);
        }
        short4v o;
        o[0] = f2bf(v.x); o[1] = f2bf(v.y); o[2] = f2bf(v.z); o[3] = f2bf(v.w);
        *reinterpret_cast<short4v*>(X + idx) = o;
    } else {
        int idx = ((bid - PACK_BLKS) * 256 + threadIdx.x) * 4;
        int z = idx / WSZ;
        int r = idx - z * WSZ;
        const float* src = (z == 0 ? Wq : (z == 1 ? Wk : Wv)) + r;
        float sc = (z == 0) ? QSF : 1.0f;   // fold qk-scale*log2e into Wq
        float4 v = *reinterpret_cast<const float4*>(src);
        short4v o;
        o[0] = f2bf(v.x * sc); o[1] = f2bf(v.y * sc);
        o[2] = f2bf(v.z * sc); o[3] = f2bf(v.w * sc);
        *reinterpret_cast<short4v*>(Wb + idx) = o;
    }
}

// ---------------------------------------------------------------------------
// Kernel 2: projection GEMM, 128x128 tile, BK=64 (12 K-steps), single-barrier
// double-buffered K-loop. Q/K/V in ONE dispatch. XOR chunk-swizzled LDS.
// Grid locality: fast dim = (n,z); XCD-chunked bijective remap (m204).
// zi==0 (Q): output pre-scaled by QSF (W and bias scaled).
// zi==2 (V): A=W-frag, B=X-frag so D[m=wcol][n=xrow]; Vt stores become
// 16-lane contiguous 32B runs along Vt's fast (token) dim.
// ---------------------------------------------------------------------------
__global__ __launch_bounds__(256) void proj4u(
    const short* __restrict__ X, const short* __restrict__ Wb,
    const float* __restrict__ bq, const float* __restrict__ bk,
    const float* __restrict__ bv,
    short* __restrict__ Qb, short* __restrict__ Kb, short* __restrict__ Vt)
{
    __shared__ short Xs[2][128 * 64];
    __shared__ short Ws[2][128 * 64];

    int tid = threadIdx.x, lane = tid & 63, wave = tid >> 6;

    // ---- XCD-aware bijective remap: nwg = 18*129 = 2322 = 8*290 + 2 ----
    int lin = blockIdx.x + 18 * blockIdx.y;
    {
        const int q = 290, r = 2;
        int xcd = lin & 7, seq = lin >> 3;
        lin = (xcd < r ? xcd * (q + 1) : r * (q + 1) + (xcd - r) * q) + seq;
    }
    int mblk = lin / 18;
    int nz   = lin - mblk * 18;
    int zi   = nz % 3;          // z fastest
    int nblk = nz / 3;
    bool vsw = (zi == 2);
    const short* W = Wb + (size_t)zi * WSZ;
    int m0 = mblk * 128, n0 = nblk * 128;

    int moff = (wave & 1) * 64, noff = (wave >> 1) * 64;
    int lr = lane & 15, lg = lane >> 4;

    // staging sources: slot s = p*256+tid -> row = s>>3, chunk c = s&7;
    // position c in LDS holds logical chunk (c ^ (row&7)) of the 64-K window.
    const short* xsrc[4];
    const short* wsrc[4];
#pragma unroll
    for (int p = 0; p < 4; ++p) {
        int s = p * 256 + tid;
        int row = s >> 3, c = s & 7;
        int col = (c ^ (row & 7)) * 8;
        xsrc[p] = X + (size_t)(m0 + row) * HID + col;
        wsrc[p] = W + (size_t)(n0 + row) * HID + col;
    }

    float4v acc[4][4];
    for (int mi = 0; mi < 4; ++mi)
        for (int ni = 0; ni < 4; ++ni)
            acc[mi][ni] = (float4v){0.f, 0.f, 0.f, 0.f};

#define PSTAGE(bufi, kt) do {                                               \
    _Pragma("unroll")                                                       \
    for (int p = 0; p < 4; ++p) {                                           \
        gl2lds16(xsrc[p] + (kt) * 64,                                       \
                 &Xs[bufi][(p * 256 + (tid & 0xC0)) * 8]);                  \
        gl2lds16(wsrc[p] + (kt) * 64,                                       \
                 &Ws[bufi][(p * 256 + (tid & 0xC0)) * 8]);                  \
    } } while (0)

    PSTAGE(0, 0);
#pragma unroll
    for (int kt = 0; kt < 12; ++kt) {
        __syncthreads();                     // drains stage(kt); prev compute done
        if (kt < 11) PSTAGE((kt + 1) & 1, kt + 1);
        const short* xb = Xs[kt & 1];
        const short* wb = Ws[kt & 1];
        short8 afl[4], afh[4], bfl[4], bfh[4];
        for (int mi = 0; mi < 4; ++mi) {
            int r = moff + mi * 16 + lr;
            int x0 = lg ^ (r & 7);
            afl[mi] = *reinterpret_cast<const short8*>(&xb[r * 64 + x0 * 8]);
            afh[mi] = *reinterpret_cast<const short8*>(&xb[r * 64 + (x0 ^ 4) * 8]);
        }
        for (int ni = 0; ni < 4; ++ni) {
            int r = noff + ni * 16 + lr;
            int x0 = lg ^ (r & 7);
            bfl[ni] = *reinterpret_cast<const short8*>(&wb[r * 64 + x0 * 8]);
            bfh[ni] = *reinterpret_cast<const short8*>(&wb[r * 64 + (x0 ^ 4) * 8]);
        }
        if (!vsw) {
            for (int mi = 0; mi < 4; ++mi)
                for (int ni = 0; ni < 4; ++ni) {
                    acc[mi][ni] = __builtin_amdgcn_mfma_f32_16x16x32_bf16(
                        afl[mi], bfl[ni], acc[mi][ni], 0, 0, 0);
                    acc[mi][ni] = __builtin_amdgcn_mfma_f32_16x16x32_bf16(
                        afh[mi], bfh[ni], acc[mi][ni], 0, 0, 0);
                }
        } else {
            for (int mi = 0; mi < 4; ++mi)
                for (int ni = 0; ni < 4; ++ni) {
                    acc[mi][ni] = __builtin_amdgcn_mfma_f32_16x16x32_bf16(
                        bfl[ni], afl[mi], acc[mi][ni], 0, 0, 0);
                    acc[mi][ni] = __builtin_amdgcn_mfma_f32_16x16x32_bf16(
                        bfh[ni], afh[mi], acc[mi][ni], 0, 0, 0);
                }
        }
    }
#undef PSTAGE

    if (!vsw) {
        short* Y = zi == 0 ? Qb : Kb;
        const float* bias = zi == 0 ? bq : bk;
        float bsc = zi == 0 ? QSF : 1.0f;
        for (int ni = 0; ni < 4; ++ni) {
            int gcol = n0 + noff + ni * 16 + lr;
            float bb = bias[gcol] * bsc;
            for (int mi = 0; mi < 4; ++mi) {
                int growb = m0 + moff + mi * 16 + lg * 4;
                for (int r = 0; r < 4; ++r)
                    Y[(size_t)(growb + r) * HID + gcol] = f2bf(acc[mi][ni][r] + bb);
            }
        }
    } else {
        // D[m=wcol = noff+ni*16+lg*4+r][n=xrow = moff+mi*16+lr]
        for (int ni = 0; ni < 4; ++ni) {
            float4 b4 = *reinterpret_cast<const float4*>(&bv[n0 + noff + ni * 16 + lg * 4]);
            const float* bbr = reinterpret_cast<const float*>(&b4);
            for (int mi = 0; mi < 4; ++mi) {
                int grow = m0 + moff + mi * 16 + lr;
                if (grow >= TOT_ROWS) continue;
                int b  = grow >= RPB ? 1 : 0;
                int rb = grow - b * RPB;
                int vr = rb < 33 ? rb : rb + 7;        // doc rows at 40+
                size_t cb = ((size_t)(b * HID + n0 + noff + ni * 16 + lg * 4)) * VT_R;
                for (int r = 0; r < 4; ++r)
                    Vt[cb + (size_t)r * VT_R + vr] = f2bf(acc[mi][ni][r] + bbr[r]);
            }
        }
    }
}

// ---------------------------------------------------------------------------
// Kernel 3: flash attention (S^T form), 192 q/block (3 s-slices of 64),
// grid (3, 384) — 10% less padded-q work than 5x128 and K/V staged 3x not
// 5x per (h,b,d).
// Pipeline: 3-buffer LDS ring, stage issued 2 tiles ahead, raw s_barrier
// with COUNTED s_waitcnt vmcnt(4) (never 0 mid-loop) + sched_barrier(0)
// (T3/T4) — no vmcnt(0) drain per tile; ~2 compute-tiles of latency cover.
// Staging addresses hoisted: tiles 0..7 are pure doc rows (linear pointer +
// compile-time offset); mixed cls/query tile 8 has a dedicated path chosen
// at compile time in the unrolled loop.
// Softmax: Q pre-scaled by SCALE*log2e; mask preloaded into QK^T acc;
// defer-max via per-lane max + __any; per-lane partial row sums reduced in
// epilogue; in-register P->A-frag repack (cvt_pk + permlane).
// Token order: doc 0..511, cls 512, query 513..544, pad 545.. (-inf mask).
// ---------------------------------------------------------------------------
__global__ __launch_bounds__(256) void attn5(
    const short* __restrict__ Qb, const short* __restrict__ Kb,
    const short* __restrict__ Vt,
    const float* __restrict__ qmask, const float* __restrict__ dmask,
    float* __restrict__ out)
{
    __shared__ short Ks[3][64 * 64];
    __shared__ short Vs[3][64 * 64];
    __shared__ float maskv[576];

    int tid  = threadIdx.x;
    int lane = tid & 63, wave = tid >> 6;

    // ---- XCD-aware remap: nwg = 3*384 = 1152 = 8*144 ----
    int lin = blockIdx.x + 3 * blockIdx.y;
    {
        int xcd = lin & 7, seq = lin >> 3;
        lin = xcd * 144 + seq;
    }
    int hbd = lin / 3;
    int qc  = lin - hbd * 3;
    int h = hbd >> 5, bd = hbd & 31;
    int b = bd >> 4, d = bd & 15;

    int lr = lane & 15, lg = lane >> 4, lk = lg * 8;
    int base = b * RPB;
    const short* vbase = Vt + (size_t)(b * HID + h * HD) * VT_R;

    // ---- hoisted staging addresses ----
    const short* kp[2]; const short* vp[2];
    const short* kp8[2]; const short* vp8[2];
    int loff[2];
#pragma unroll
    for (int p = 0; p < 2; ++p) {
        int s2 = p * 256 + tid;
        int r = s2 >> 3, c = s2 & 7;
        int colsw = (c ^ (r & 7)) * 8;
        // tiles 0..7: token = kt*64 + r, all doc rows (linear in kt)
        kp[p] = Kb + (size_t)(base + 33 + d * SL + r) * HID + h * HD + colsw;
        // V: tc = kt*64 + colsw-chunk (<512) -> vr = 40 + d*SL + tc
        vp[p] = vbase + (size_t)r * VT_R + 40 + d * SL + colsw;
        // tile 8: token t = 512+r -> row = base + min(r,32)  (cls/query/clamp)
        int r8 = r > 32 ? 32 : r;
        kp8[p] = Kb + (size_t)(base + r8) * HID + h * HD + colsw;
        // V tile 8: tc = 512 + chunk -> vr = chunk
        vp8[p] = vbase + (size_t)r * VT_R + colsw;
        loff[p] = (p * 256 + (tid & 0xC0)) * 8;
    }

#define ALIN(bufi, kt) do {                                       \
    gl2lds16(kp[0] + (size_t)(kt) * 64 * HID, &Ks[bufi][loff[0]]);\
    gl2lds16(kp[1] + (size_t)(kt) * 64 * HID, &Ks[bufi][loff[1]]);\
    gl2lds16(vp[0] + (kt) * 64, &Vs[bufi][loff[0]]);              \
    gl2lds16(vp[1] + (kt) * 64, &Vs[bufi][loff[1]]); } while (0)
#define A8(bufi) do {                                             \
    gl2lds16(kp8[0], &Ks[bufi][loff[0]]);                         \
    gl2lds16(kp8[1], &Ks[bufi][loff[1]]);                         \
    gl2lds16(vp8[0], &Vs[bufi][loff[0]]);                         \
    gl2lds16(vp8[1], &Vs[bufi][loff[1]]); } while (0)

    ALIN(0, 0);
    ALIN(1, 1);

    for (int i = tid; i < 576; i += 256) {
        float mv;
        if (i < 512)       mv = dmask[(size_t)(b * D_ + d) * SL + i];
        else if (i == 512) mv = 0.f;
        else if (i < 545)  mv = qmask[b * QL + (i - 513)];
        else               mv = -INFINITY;
        maskv[i] = mv * LOG2E;
    }

    short8 bq0[3], bq1[3];
#pragma unroll
    for (int s = 0; s < 3; ++s) {
        int qtok = qc * 192 + s * 64 + wave * 16 + lr;
        int qrow = qtok < 512 ? base + 33 + d * SL + qtok : base + qtok - 512;
        const short* qp = Qb + (size_t)qrow * HID + h * HD + lk;
        bq0[s] = *reinterpret_cast<const short8*>(qp);
        bq1[s] = *reinterpret_cast<const short8*>(qp + 32);
    }

    float m_i[3] = {-1e30f, -1e30f, -1e30f};
    float lp[3]  = {0.f, 0.f, 0.f};     // per-LANE partial row sums
    float4v o[3][4];
    for (int s = 0; s < 3; ++s)
        for (int nt = 0; nt < 4; ++nt) o[s][nt] = (float4v){0.f, 0.f, 0.f, 0.f};

    __syncthreads();    // full drain once: stage0/1 landed, maskv visible

#pragma unroll
    for (int kt = 0; kt < 9; ++kt) {
        if (kt >= 1) {
            // counted wait: stage(kt) complete, stage(kt+1) stays in flight
            if (kt == 8) { asm volatile("s_waitcnt vmcnt(0)" ::: "memory"); }
            else         { asm volatile("s_waitcnt vmcnt(4)" ::: "memory"); }
            __builtin_amdgcn_s_barrier();
            __builtin_amdgcn_sched_barrier(0);
        }
        if (kt < 6)       ALIN((kt + 2) % 3, kt + 2);
        else if (kt == 6) A8((kt + 2) % 3);

        const short* kb   = Ks[kt % 3];
        const short* vbuf = Vs[kt % 3];

        // per-kt hoists (shared across the 3 s-slices)
        float4v mk[4];
        short8 kf0[4], kf1[4];
#pragma unroll
        for (int nt = 0; nt < 4; ++nt) {
            mk[nt] = *reinterpret_cast<const float4v*>(
                &maskv[kt * 64 + nt * 16 + lg * 4]);
            int r = nt * 16 + lr;
            int x0 = lg ^ (r & 7);
            kf0[nt] = *reinterpret_cast<const short8*>(&kb[r * 64 + x0 * 8]);
            kf1[nt] = *reinterpret_cast<const short8*>(&kb[r * 64 + (x0 ^ 4) * 8]);
        }

#pragma unroll
        for (int s = 0; s < 3; ++s) {
            // ---- QK^T: lane holds P[key = kt*64+nt*16+lg*4+r][q = lr] ----
            float p4[4][4];
            __builtin_amdgcn_s_setprio(1);
            for (int nt = 0; nt < 4; ++nt) {
                float4v z = mk[nt];
                z = __builtin_amdgcn_mfma_f32_16x16x32_bf16(kf0[nt], bq0[s], z, 0, 0, 0);
                z = __builtin_amdgcn_mfma_f32_16x16x32_bf16(kf1[nt], bq1[s], z, 0, 0, 0);
                for (int r = 0; r < 4; ++r) p4[nt][r] = z[r];
            }
            __builtin_amdgcn_s_setprio(0);

            // ---- per-LANE max (max3-fusable); no cross-lane in common path ----
            float c0 = fmaxf(fmaxf(p4[0][0], p4[0][1]), p4[0][2]);
            float c1 = fmaxf(fmaxf(p4[0][3], p4[1][0]), p4[1][1]);
            float c2 = fmaxf(fmaxf(p4[1][2], p4[1][3]), p4[2][0]);
            float c3 = fmaxf(fmaxf(p4[2][1], p4[2][2]), p4[2][3]);
            float c4 = fmaxf(fmaxf(p4[3][0], p4[3][1]), p4[3][2]);
            float lmax = fmaxf(fmaxf(fmaxf(c0, c1), fmaxf(c2, c3)),
                               fmaxf(c4, p4[3][3]));

            // ---- defer-max: rescale only if some row grows past m+8 ----
            if (__any(lmax > m_i[s] + 8.0f)) {
                float tmx = fmaxf(lmax, __shfl_xor(lmax, 16));
                tmx = fmaxf(tmx, __shfl_xor(tmx, 32));       // row max (q=lr)
                float mnew = fmaxf(m_i[s], tmx);
                float alpha = exp2f(m_i[s] - mnew);
                m_i[s] = mnew;
                lp[s] *= alpha;
                float al[4];
                for (int r = 0; r < 4; ++r) al[r] = __shfl(alpha, lg * 4 + r);
                for (int nt = 0; nt < 4; ++nt)
                    for (int r = 0; r < 4; ++r) o[s][nt][r] *= al[r];
            }

            // ---- exp2 + per-lane partial sum (P bounded by 2^8) ----
            for (int nt = 0; nt < 4; ++nt)
                for (int r = 0; r < 4; ++r)
                    p4[nt][r] = exp2f(p4[nt][r] - m_i[s]);
            float s0 = (p4[0][0] + p4[0][1]) + (p4[0][2] + p4[0][3]);
            float s1 = (p4[1][0] + p4[1][1]) + (p4[1][2] + p4[1][3]);
            float s2 = (p4[2][0] + p4[2][1]) + (p4[2][2] + p4[2][3]);
            float s3 = (p4[3][0] + p4[3][1]) + (p4[3][2] + p4[3][3]);
            lp[s] += (s0 + s1) + (s2 + s3);

            // ---- in-register P -> PV A-fragment repack ----
            unsigned int wa[4], wbv[4];
            for (int nt = 0; nt < 4; ++nt) {
                wa[nt]  = cvtpk(p4[nt][0], p4[nt][1]);
                wbv[nt] = cvtpk(p4[nt][2], p4[nt][3]);
            }
            uint2v tA01 = __builtin_amdgcn_permlane32_swap(wa[0],  wa[1],  false, false);
            uint2v uA01 = __builtin_amdgcn_permlane16_swap(tA01[0], tA01[1], false, false);
            uint2v tB01 = __builtin_amdgcn_permlane32_swap(wbv[0], wbv[1], false, false);
            uint2v uB01 = __builtin_amdgcn_permlane16_swap(tB01[0], tB01[1], false, false);
            uint2v tA23 = __builtin_amdgcn_permlane32_swap(wa[2],  wa[3],  false, false);
            uint2v uA23 = __builtin_amdgcn_permlane16_swap(tA23[0], tA23[1], false, false);
            uint2v tB23 = __builtin_amdgcn_permlane32_swap(wbv[2], wbv[3], false, false);
            uint2v uB23 = __builtin_amdgcn_permlane16_swap(tB23[0], tB23[1], false, false);

            union { unsigned int u[4]; short8 s8; } A0, A1;
            A0.u[0] = uA01[0]; A0.u[1] = uB01[0]; A0.u[2] = uA01[1]; A0.u[3] = uB01[1];
            A1.u[0] = uA23[0]; A1.u[1] = uB23[0]; A1.u[2] = uA23[1]; A1.u[3] = uB23[1];
            short8 ap0 = A0.s8;
            short8 ap1 = A1.s8;

            // ---- PV ----
            __builtin_amdgcn_s_setprio(1);
            for (int nt = 0; nt < 4; ++nt) {
                int rd = nt * 16 + lr;
                int x0 = lg ^ (rd & 7);
                short8 bv0 = *reinterpret_cast<const short8*>(&vbuf[rd * 64 + x0 * 8]);
                short8 bv1 = *reinterpret_cast<const short8*>(&vbuf[rd * 64 + (x0 ^ 4) * 8]);
                o[s][nt] = __builtin_amdgcn_mfma_f32_16x16x32_bf16(ap0, bv0, o[s][nt], 0, 0, 0);
                o[s][nt] = __builtin_amdgcn_mfma_f32_16x16x32_bf16(ap1, bv1, o[s][nt], 0, 0, 0);
            }
            __builtin_amdgcn_s_setprio(0);
        }
    }
#undef ALIN
#undef A8

    for (int s = 0; s < 3; ++s) {
        float lt = lp[s];
        lt += __shfl_xor(lt, 16);
        lt += __shfl_xor(lt, 32);           // row total (q=lr), replicated
        float li[4];
        for (int r = 0; r < 4; ++r) li[r] = __shfl(lt, lg * 4 + r);
        for (int r = 0; r < 4; ++r) {
            int t = qc * 192 + s * 64 + wave * 16 + lg * 4 + r;
            if (t >= SEQ) continue;
            int seq = t < 512 ? 33 + t : (t == 512 ? 0 : t - 512);
            float inv = 1.f / li[r];
            float* op = out + ((size_t)(bd * SEQ + seq)) * HID + h * HD + lr;
            for (int nt = 0; nt < 4; ++nt)
                op[nt * 16] = o[s][nt][r] * inv;
        }
    }
}

// ---------------------------------------------------------------------------
extern "C" void kernel_launch(void* const* d_in, const int* in_sizes, int n_in,
                              void* d_out, int out_size, void* d_ws, size_t ws_size,
                              hipStream_t stream)
{
    const float* cls   = (const float*)d_in[0];
    const float* query = (const float*)d_in[1];
    const float* doc   = (const float*)d_in[2];
    const float* qmask = (const float*)d_in[3];
    const float* dmask = (const float*)d_in[4];
    const float* Wq = (const float*)d_in[5];
    const float* bq = (const float*)d_in[6];
    const float* Wk = (const float*)d_in[7];
    const float* bk = (const float*)d_in[8];
    const float* Wv = (const float*)d_in[9];
    const float* bv = (const float*)d_in[10];
    float* out = (float*)d_out;

    short* X  = (short*)d_ws;
    size_t seg = (size_t)PAD_ROWS * HID;
    short* Qb = X + seg;
    short* Kb = Qb + seg;
    short* Vt = Kb + seg;                 // 2*768*8256 == seg
    short* Wb = (short*)d_out;            // scratch; attn5 overwrites all of out

    pack_all<<<dim3(PACK_BLKS + WPACK_BLKS), 256, 0, stream>>>(
        cls, query, doc, Wq, Wk, Wv, X, Wb);
    proj4u<<<dim3(18, 129, 1), 256, 0, stream>>>(X, Wb, bq, bk, bv, Qb, Kb, Vt);
    attn5<<<dim3(3, NH * 32, 1), 256, 0, stream>>>(Qb, Kb, Vt, qmask, dmask, out);
}

// Round 6
// 270.519 us; speedup vs baseline: 1.2743x; 1.0287x over previous
//
#include <hip/hip_runtime.h>
#include <hip/hip_bf16.h>

#define NH      12
#define HD      64
#define HID     768
#define B_      2
#define D_      16
#define QL      32
#define SL      512
#define SEQ     545
#define RPB     8225
#define TOT_ROWS 16450
#define PAD_ROWS 16512       // 129*128
#define VT_R    8256         // Vt rows/batch: cls=0, query 1..32, doc d at 40+d*512
#define WSZ     589824       // 768*768
#define SCALE_  0.125f
#define LOG2E   1.4426950408889634f
#define QSF     0.18033688011112042f   // SCALE_*LOG2E, folded into Wq/bq

typedef __attribute__((ext_vector_type(8))) short short8;
typedef __attribute__((ext_vector_type(4))) short short4v;
typedef __attribute__((ext_vector_type(4))) float float4v;
typedef __attribute__((ext_vector_type(2))) unsigned int uint2v;

__device__ __forceinline__ short f2bf(float f) {
    __hip_bfloat16 h = __float2bfloat16(f);
    short s; __builtin_memcpy(&s, &h, 2);
    return s;
}

// v_cvt_pk_bf16_f32: lo16=bf16(a), hi16=bf16(b) — no builtin on gfx950
__device__ __forceinline__ unsigned int cvtpk(float a, float b) {
    unsigned int r;
    asm("v_cvt_pk_bf16_f32 %0, %1, %2" : "=v"(r) : "v"(a), "v"(b));
    return r;
}

// async global->LDS 16B/lane; lds base wave-uniform (HW adds lane*16)
__device__ __forceinline__ void gl2lds16(const short* g, short* l) {
    __builtin_amdgcn_global_load_lds(
        (const __attribute__((address_space(1))) void*)g,
        (__attribute__((address_space(3))) void*)l, 16, 0, 0);
}

#define PACK_BLKS  12384     // PAD_ROWS*HID/4/256
#define WPACK_BLKS 1728      // 3*WSZ/4/256

// ---------------------------------------------------------------------------
// Kernel 1 (fused): gather cls/query/doc fp32 -> bf16 X [PAD_ROWS x 768],
// and W fp32 -> bf16 (Wq pre-scaled by SCALE*log2e; Wb parked in d_out).
// ---------------------------------------------------------------------------
__global__ __launch_bounds__(256) void pack_all(
    const float* __restrict__ cls, const float* __restrict__ query,
    const float* __restrict__ doc,
    const float* __restrict__ Wq, const float* __restrict__ Wk,
    const float* __restrict__ Wv,
    short* __restrict__ X, short* __restrict__ Wb)
{
    int bid = blockIdx.x;
    if (bid < PACK_BLKS) {
        int idx = (bid * 256 + threadIdx.x) * 4;
        int row = idx / HID;
        int col = idx - row * HID;
        float4 v = make_float4(0.f, 0.f, 0.f, 0.f);
        if (row < TOT_ROWS) {
            int b = row / RPB;
            int r = row - b * RPB;
            const float* src;
            if (r == 0)        src = cls   + b * HID + col;
            else if (r < 33)   src = query + ((size_t)(b * QL + (r - 1))) * HID + col;
            else               src = doc   + ((size_t)(b * (D_ * SL) + (r - 33))) * HID + col;
            v = *reinterpret_cast<const float4*>(src);
        }
        short4v o;
        o[0] = f2bf(v.x); o[1] = f2bf(v.y); o[2] = f2bf(v.z); o[3] = f2bf(v.w);
        *reinterpret_cast<short4v*>(X + idx) = o;
    } else {
        int idx = ((bid - PACK_BLKS) * 256 + threadIdx.x) * 4;
        int z = idx / WSZ;
        int r = idx - z * WSZ;
        const float* src = (z == 0 ? Wq : (z == 1 ? Wk : Wv)) + r;
        float sc = (z == 0) ? QSF : 1.0f;   // fold qk-scale*log2e into Wq
        float4 v = *reinterpret_cast<const float4*>(src);
        short4v o;
        o[0] = f2bf(v.x * sc); o[1] = f2bf(v.y * sc);
        o[2] = f2bf(v.z * sc); o[3] = f2bf(v.w * sc);
        *reinterpret_cast<short4v*>(Wb + idx) = o;
    }
}

// ---------------------------------------------------------------------------
// Kernel 2: projection GEMM, 128x128 tile, BK=64 (12 K-steps), single-barrier
// double-buffered K-loop. Q/K/V in ONE dispatch. XOR chunk-swizzled LDS.
// Grid locality: fast dim = (n,z); XCD-chunked bijective remap (m204).
// zi==0 (Q): output pre-scaled by QSF (W and bias scaled).
// zi==2 (V): A=W-frag, B=X-frag so D[m=wcol][n=xrow]; Vt stores become
// 16-lane contiguous 32B runs along Vt's fast (token) dim.
// ---------------------------------------------------------------------------
__global__ __launch_bounds__(256) void proj4u(
    const short* __restrict__ X, const short* __restrict__ Wb,
    const float* __restrict__ bq, const float* __restrict__ bk,
    const float* __restrict__ bv,
    short* __restrict__ Qb, short* __restrict__ Kb, short* __restrict__ Vt)
{
    __shared__ short Xs[2][128 * 64];
    __shared__ short Ws[2][128 * 64];

    int tid = threadIdx.x, lane = tid & 63, wave = tid >> 6;

    // ---- XCD-aware bijective remap: nwg = 18*129 = 2322 = 8*290 + 2 ----
    int lin = blockIdx.x + 18 * blockIdx.y;
    {
        const int q = 290, r = 2;
        int xcd = lin & 7, seq = lin >> 3;
        lin = (xcd < r ? xcd * (q + 1) : r * (q + 1) + (xcd - r) * q) + seq;
    }
    int mblk = lin / 18;
    int nz   = lin - mblk * 18;
    int zi   = nz % 3;          // z fastest
    int nblk = nz / 3;
    bool vsw = (zi == 2);
    const short* W = Wb + (size_t)zi * WSZ;
    int m0 = mblk * 128, n0 = nblk * 128;

    int moff = (wave & 1) * 64, noff = (wave >> 1) * 64;
    int lr = lane & 15, lg = lane >> 4;

    // staging sources: slot s = p*256+tid -> row = s>>3, chunk c = s&7;
    // position c in LDS holds logical chunk (c ^ (row&7)) of the 64-K window.
    const short* xsrc[4];
    const short* wsrc[4];
#pragma unroll
    for (int p = 0; p < 4; ++p) {
        int s = p * 256 + tid;
        int row = s >> 3, c = s & 7;
        int col = (c ^ (row & 7)) * 8;
        xsrc[p] = X + (size_t)(m0 + row) * HID + col;
        wsrc[p] = W + (size_t)(n0 + row) * HID + col;
    }

    float4v acc[4][4];
    for (int mi = 0; mi < 4; ++mi)
        for (int ni = 0; ni < 4; ++ni)
            acc[mi][ni] = (float4v){0.f, 0.f, 0.f, 0.f};

#define PSTAGE(bufi, kt) do {                                               \
    _Pragma("unroll")                                                       \
    for (int p = 0; p < 4; ++p) {                                           \
        gl2lds16(xsrc[p] + (kt) * 64,                                       \
                 &Xs[bufi][(p * 256 + (tid & 0xC0)) * 8]);                  \
        gl2lds16(wsrc[p] + (kt) * 64,                                       \
                 &Ws[bufi][(p * 256 + (tid & 0xC0)) * 8]);                  \
    } } while (0)

    PSTAGE(0, 0);
#pragma unroll
    for (int kt = 0; kt < 12; ++kt) {
        __syncthreads();                     // drains stage(kt); prev compute done
        if (kt < 11) PSTAGE((kt + 1) & 1, kt + 1);
        const short* xb = Xs[kt & 1];
        const short* wb = Ws[kt & 1];
        short8 afl[4], afh[4], bfl[4], bfh[4];
        for (int mi = 0; mi < 4; ++mi) {
            int r = moff + mi * 16 + lr;
            int x0 = lg ^ (r & 7);
            afl[mi] = *reinterpret_cast<const short8*>(&xb[r * 64 + x0 * 8]);
            afh[mi] = *reinterpret_cast<const short8*>(&xb[r * 64 + (x0 ^ 4) * 8]);
        }
        for (int ni = 0; ni < 4; ++ni) {
            int r = noff + ni * 16 + lr;
            int x0 = lg ^ (r & 7);
            bfl[ni] = *reinterpret_cast<const short8*>(&wb[r * 64 + x0 * 8]);
            bfh[ni] = *reinterpret_cast<const short8*>(&wb[r * 64 + (x0 ^ 4) * 8]);
        }
        if (!vsw) {
            for (int mi = 0; mi < 4; ++mi)
                for (int ni = 0; ni < 4; ++ni) {
                    acc[mi][ni] = __builtin_amdgcn_mfma_f32_16x16x32_bf16(
                        afl[mi], bfl[ni], acc[mi][ni], 0, 0, 0);
                    acc[mi][ni] = __builtin_amdgcn_mfma_f32_16x16x32_bf16(
                        afh[mi], bfh[ni], acc[mi][ni], 0, 0, 0);
                }
        } else {
            for (int mi = 0; mi < 4; ++mi)
                for (int ni = 0; ni < 4; ++ni) {
                    acc[mi][ni] = __builtin_amdgcn_mfma_f32_16x16x32_bf16(
                        bfl[ni], afl[mi], acc[mi][ni], 0, 0, 0);
                    acc[mi][ni] = __builtin_amdgcn_mfma_f32_16x16x32_bf16(
                        bfh[ni], afh[mi], acc[mi][ni], 0, 0, 0);
                }
        }
    }
#undef PSTAGE

    if (!vsw) {
        short* Y = zi == 0 ? Qb : Kb;
        const float* bias = zi == 0 ? bq : bk;
        float bsc = zi == 0 ? QSF : 1.0f;
        for (int ni = 0; ni < 4; ++ni) {
            int gcol = n0 + noff + ni * 16 + lr;
            float bb = bias[gcol] * bsc;
            for (int mi = 0; mi < 4; ++mi) {
                int growb = m0 + moff + mi * 16 + lg * 4;
                for (int r = 0; r < 4; ++r)
                    Y[(size_t)(growb + r) * HID + gcol] = f2bf(acc[mi][ni][r] + bb);
            }
        }
    } else {
        // D[m=wcol = noff+ni*16+lg*4+r][n=xrow = moff+mi*16+lr]
        for (int ni = 0; ni < 4; ++ni) {
            float4 b4 = *reinterpret_cast<const float4*>(&bv[n0 + noff + ni * 16 + lg * 4]);
            const float* bbr = reinterpret_cast<const float*>(&b4);
            for (int mi = 0; mi < 4; ++mi) {
                int grow = m0 + moff + mi * 16 + lr;
                if (grow >= TOT_ROWS) continue;
                int b  = grow >= RPB ? 1 : 0;
                int rb = grow - b * RPB;
                int vr = rb < 33 ? rb : rb + 7;        // doc rows at 40+
                size_t cb = ((size_t)(b * HID + n0 + noff + ni * 16 + lg * 4)) * VT_R;
                for (int r = 0; r < 4; ++r)
                    Vt[cb + (size_t)r * VT_R + vr] = f2bf(acc[mi][ni][r] + bbr[r]);
            }
        }
    }
}

// ---------------------------------------------------------------------------
// Kernel 3: flash attention (S^T form), 192 q/block, **768 threads / 12
// waves**: each wave owns one (s-slice, 16-q) strip — 3x the resident waves
// of the 4-wave version for the same grid (occupancy was the round-5 limit:
// 17.5%, grid couldn't fill the machine).
// Staging: tid<512 stages one K slot + one V slot (wave-uniform predicate,
// waves 0..7). 3-buffer ring, counted s_waitcnt vmcnt(2) (= stage(kt+1)'s
// 2 loads stay in flight) + raw s_barrier + sched_barrier(0).
// Softmax: Q pre-scaled; mask preloaded into QK^T acc; defer-max via
// per-lane max + __any; per-lane partial sums reduced in epilogue;
// in-register P->A-frag repack (cvt_pk + permlane).
// Token order: doc 0..511, cls 512, query 513..544, pad 545.. (-inf mask).
// ---------------------------------------------------------------------------
__global__ __launch_bounds__(768) void attn6(
    const short* __restrict__ Qb, const short* __restrict__ Kb,
    const short* __restrict__ Vt,
    const float* __restrict__ qmask, const float* __restrict__ dmask,
    float* __restrict__ out)
{
    __shared__ short Ks[3][64 * 64];
    __shared__ short Vs[3][64 * 64];
    __shared__ float maskv[576];

    int tid  = threadIdx.x;
    int lane = tid & 63, wave = tid >> 6;

    // ---- XCD-aware remap: nwg = 3*384 = 1152 = 8*144 ----
    int lin = blockIdx.x + 3 * blockIdx.y;
    {
        int xcd = lin & 7, seq = lin >> 3;
        lin = xcd * 144 + seq;
    }
    int hbd = lin / 3;
    int qc  = lin - hbd * 3;
    int h = hbd >> 5, bd = hbd & 31;
    int b = bd >> 4, d = bd & 15;

    int lr = lane & 15, lg = lane >> 4, lk = lg * 8;
    int sidx = wave >> 2, wq = wave & 3;      // wave -> (s-slice, q-strip)
    int base = b * RPB;
    const short* vbase = Vt + (size_t)(b * HID + h * HD) * VT_R;

    // ---- hoisted staging addresses (tid<512 stages; waves 0..7) ----
    bool stg = tid < 512;                     // wave-uniform
    int loffK = (tid & 0x1C0) * 8;            // wave-uniform LDS base
    const short *kp = Kb, *vp = Vt, *kp8 = Kb, *vp8 = Vt;
    {
        int r = tid >> 3, c = tid & 7;
        int colsw = (c ^ (r & 7)) * 8;
        if (stg) {
            // tiles 0..7: token = kt*64 + r, all doc rows (linear in kt)
            kp  = Kb + (size_t)(base + 33 + d * SL + r) * HID + h * HD + colsw;
            vp  = vbase + (size_t)r * VT_R + 40 + d * SL + colsw;
            // tile 8: token 512+r -> row base+min(r,32); V: vr = chunk
            int r8 = r > 32 ? 32 : r;
            kp8 = Kb + (size_t)(base + r8) * HID + h * HD + colsw;
            vp8 = vbase + (size_t)r * VT_R + colsw;
        }
    }

#define ALIN(bufi, kt) do { if (stg) {                            \
    gl2lds16(kp + (size_t)(kt) * 64 * HID, &Ks[bufi][loffK]);     \
    gl2lds16(vp + (kt) * 64, &Vs[bufi][loffK]); } } while (0)
#define A8(bufi) do { if (stg) {                                  \
    gl2lds16(kp8, &Ks[bufi][loffK]);                              \
    gl2lds16(vp8, &Vs[bufi][loffK]); } } while (0)

    ALIN(0, 0);
    ALIN(1, 1);

    if (tid < 576) {
        int i = tid;
        float mv;
        if (i < 512)       mv = dmask[(size_t)(b * D_ + d) * SL + i];
        else if (i == 512) mv = 0.f;
        else if (i < 545)  mv = qmask[b * QL + (i - 513)];
        else               mv = -INFINITY;
        maskv[i] = mv * LOG2E;
    }

    short8 bq0, bq1;
    {
        int qtok = qc * 192 + sidx * 64 + wq * 16 + lr;
        int qrow = qtok < 512 ? base + 33 + d * SL + qtok : base + qtok - 512;
        const short* qp = Qb + (size_t)qrow * HID + h * HD + lk;
        bq0 = *reinterpret_cast<const short8*>(qp);
        bq1 = *reinterpret_cast<const short8*>(qp + 32);
    }

    float m_i = -1e30f;
    float lp  = 0.f;                    // per-LANE partial row sum
    float4v o[4];
    for (int nt = 0; nt < 4; ++nt) o[nt] = (float4v){0.f, 0.f, 0.f, 0.f};

    __syncthreads();    // full drain once: stage0/1 landed, maskv visible

#pragma unroll
    for (int kt = 0; kt < 9; ++kt) {
        if (kt >= 1) {
            // counted wait: stage(kt) complete, stage(kt+1) stays in flight
            if (kt == 8) { asm volatile("s_waitcnt vmcnt(0)" ::: "memory"); }
            else         { asm volatile("s_waitcnt vmcnt(2)" ::: "memory"); }
            __builtin_amdgcn_s_barrier();
            __builtin_amdgcn_sched_barrier(0);
        }
        if (kt < 6)       ALIN((kt + 2) % 3, kt + 2);
        else if (kt == 6) A8((kt + 2) % 3);

        const short* kb   = Ks[kt % 3];
        const short* vbuf = Vs[kt % 3];

        // ---- QK^T: lane holds P[key = kt*64+nt*16+lg*4+r][q = lr];
        //      mask pre-loaded into the accumulator, Q pre-scaled ----
        float p4[4][4];
        short8 kf0[4], kf1[4];
#pragma unroll
        for (int nt = 0; nt < 4; ++nt) {
            int r = nt * 16 + lr;
            int x0 = lg ^ (r & 7);
            kf0[nt] = *reinterpret_cast<const short8*>(&kb[r * 64 + x0 * 8]);
            kf1[nt] = *reinterpret_cast<const short8*>(&kb[r * 64 + (x0 ^ 4) * 8]);
        }
        __builtin_amdgcn_s_setprio(1);
#pragma unroll
        for (int nt = 0; nt < 4; ++nt) {
            float4v z = *reinterpret_cast<const float4v*>(
                &maskv[kt * 64 + nt * 16 + lg * 4]);
            z = __builtin_amdgcn_mfma_f32_16x16x32_bf16(kf0[nt], bq0, z, 0, 0, 0);
            z = __builtin_amdgcn_mfma_f32_16x16x32_bf16(kf1[nt], bq1, z, 0, 0, 0);
            for (int r = 0; r < 4; ++r) p4[nt][r] = z[r];
        }
        __builtin_amdgcn_s_setprio(0);

        // ---- per-LANE max (max3-fusable); no cross-lane in common path ----
        float c0 = fmaxf(fmaxf(p4[0][0], p4[0][1]), p4[0][2]);
        float c1 = fmaxf(fmaxf(p4[0][3], p4[1][0]), p4[1][1]);
        float c2 = fmaxf(fmaxf(p4[1][2], p4[1][3]), p4[2][0]);
        float c3 = fmaxf(fmaxf(p4[2][1], p4[2][2]), p4[2][3]);
        float c4 = fmaxf(fmaxf(p4[3][0], p4[3][1]), p4[3][2]);
        float lmax = fmaxf(fmaxf(fmaxf(c0, c1), fmaxf(c2, c3)),
                           fmaxf(c4, p4[3][3]));

        // ---- defer-max: rescale only if some row grows past m+8 ----
        if (__any(lmax > m_i + 8.0f)) {
            float tmx = fmaxf(lmax, __shfl_xor(lmax, 16));
            tmx = fmaxf(tmx, __shfl_xor(tmx, 32));       // row max (q=lr)
            float mnew = fmaxf(m_i, tmx);
            float alpha = exp2f(m_i - mnew);
            m_i = mnew;
            lp *= alpha;
            float al[4];
            for (int r = 0; r < 4; ++r) al[r] = __shfl(alpha, lg * 4 + r);
            for (int nt = 0; nt < 4; ++nt)
                for (int r = 0; r < 4; ++r) o[nt][r] *= al[r];
        }

        // ---- exp2 + per-lane partial sum (P bounded by 2^8) ----
        for (int nt = 0; nt < 4; ++nt)
            for (int r = 0; r < 4; ++r)
                p4[nt][r] = exp2f(p4[nt][r] - m_i);
        float s0 = (p4[0][0] + p4[0][1]) + (p4[0][2] + p4[0][3]);
        float s1 = (p4[1][0] + p4[1][1]) + (p4[1][2] + p4[1][3]);
        float s2 = (p4[2][0] + p4[2][1]) + (p4[2][2] + p4[2][3]);
        float s3 = (p4[3][0] + p4[3][1]) + (p4[3][2] + p4[3][3]);
        lp += (s0 + s1) + (s2 + s3);

        // ---- in-register P -> PV A-fragment repack ----
        unsigned int wa[4], wbv[4];
        for (int nt = 0; nt < 4; ++nt) {
            wa[nt]  = cvtpk(p4[nt][0], p4[nt][1]);
            wbv[nt] = cvtpk(p4[nt][2], p4[nt][3]);
        }
        uint2v tA01 = __builtin_amdgcn_permlane32_swap(wa[0],  wa[1],  false, false);
        uint2v uA01 = __builtin_amdgcn_permlane16_swap(tA01[0], tA01[1], false, false);
        uint2v tB01 = __builtin_amdgcn_permlane32_swap(wbv[0], wbv[1], false, false);
        uint2v uB01 = __builtin_amdgcn_permlane16_swap(tB01[0], tB01[1], false, false);
        uint2v tA23 = __builtin_amdgcn_permlane32_swap(wa[2],  wa[3],  false, false);
        uint2v uA23 = __builtin_amdgcn_permlane16_swap(tA23[0], tA23[1], false, false);
        uint2v tB23 = __builtin_amdgcn_permlane32_swap(wbv[2], wbv[3], false, false);
        uint2v uB23 = __builtin_amdgcn_permlane16_swap(tB23[0], tB23[1], false, false);

        union { unsigned int u[4]; short8 s8; } A0, A1;
        A0.u[0] = uA01[0]; A0.u[1] = uB01[0]; A0.u[2] = uA01[1]; A0.u[3] = uB01[1];
        A1.u[0] = uA23[0]; A1.u[1] = uB23[0]; A1.u[2] = uA23[1]; A1.u[3] = uB23[1];
        short8 ap0 = A0.s8;
        short8 ap1 = A1.s8;

        // ---- PV ----
        __builtin_amdgcn_s_setprio(1);
#pragma unroll
        for (int nt = 0; nt < 4; ++nt) {
            int rd = nt * 16 + lr;
            int x0 = lg ^ (rd & 7);
            short8 bv0 = *reinterpret_cast<const short8*>(&vbuf[rd * 64 + x0 * 8]);
            short8 bv1 = *reinterpret_cast<const short8*>(&vbuf[rd * 64 + (x0 ^ 4) * 8]);
            o[nt] = __builtin_amdgcn_mfma_f32_16x16x32_bf16(ap0, bv0, o[nt], 0, 0, 0);
            o[nt] = __builtin_amdgcn_mfma_f32_16x16x32_bf16(ap1, bv1, o[nt], 0, 0, 0);
        }
        __builtin_amdgcn_s_setprio(0);
    }
#undef ALIN
#undef A8

    {
        float lt = lp;
        lt += __shfl_xor(lt, 16);
        lt += __shfl_xor(lt, 32);           // row total (q=lr), replicated
        float li[4];
        for (int r = 0; r < 4; ++r) li[r] = __shfl(lt, lg * 4 + r);
        for (int r = 0; r < 4; ++r) {
            int t = qc * 192 + sidx * 64 + wq * 16 + lg * 4 + r;
            if (t >= SEQ) continue;
            int seq = t < 512 ? 33 + t : (t == 512 ? 0 : t - 512);
            float inv = 1.f / li[r];
            float* op = out + ((size_t)(bd * SEQ + seq)) * HID + h * HD + lr;
            for (int nt = 0; nt < 4; ++nt)
                op[nt * 16] = o[nt][r] * inv;
        }
    }
}

// ---------------------------------------------------------------------------
extern "C" void kernel_launch(void* const* d_in, const int* in_sizes, int n_in,
                              void* d_out, int out_size, void* d_ws, size_t ws_size,
                              hipStream_t stream)
{
    const float* cls   = (const float*)d_in[0];
    const float* query = (const float*)d_in[1];
    const float* doc   = (const float*)d_in[2];
    const float* qmask = (const float*)d_in[3];
    const float* dmask = (const float*)d_in[4];
    const float* Wq = (const float*)d_in[5];
    const float* bq = (const float*)d_in[6];
    const float* Wk = (const float*)d_in[7];
    const float* bk = (const float*)d_in[8];
    const float* Wv = (const float*)d_in[9];
    const float* bv = (const float*)d_in[10];
    float* out = (float*)d_out;

    short* X  = (short*)d_ws;
    size_t seg = (size_t)PAD_ROWS * HID;
    short* Qb = X + seg;
    short* Kb = Qb + seg;
    short* Vt = Kb + seg;                 // 2*768*8256 == seg
    short* Wb = (short*)d_out;            // scratch; attn6 overwrites all of out

    pack_all<<<dim3(PACK_BLKS + WPACK_BLKS), 256, 0, stream>>>(
        cls, query, doc, Wq, Wk, Wv, X, Wb);
    proj4u<<<dim3(18, 129, 1), 256, 0, stream>>>(X, Wb, bq, bk, bv, Qb, Kb, Vt);
    attn6<<<dim3(3, NH * 32, 1), 768, 0, stream>>>(Qb, Kb, Vt, qmask, dmask, out);
}